// Round 2
// baseline (657.470 us; speedup 1.0000x reference)
//
#include <hip/hip_runtime.h>
#include <hip/hip_fp16.h>

// Layout: per level, fp16 ROW-PAIR repack R[y][x] = half2(img[y][x], img[min(y+1,S-1)][x]).
// One bilinear quad = one 8-byte load, zero-padding folded into weights.
//
// This round: the sample kernel is vector-memory REQUEST-RATE bound (round-1
// evidence: FETCH -19% but dur +5%), not bandwidth bound. Random uv => every
// lane-gather is a distinct cache line (~5 cy each). Fix: segmented counting
// sort of points by 64x64 spatial bin (4096 bins; ~2048 pts/bin => 4KB level-1
// tile per bin, L1-resident, heavy line coalescing on levels 2-4). Segments of
// 512K points keep the out[idx] scatter inside a 2MB L2-resident window.

typedef unsigned int u32x2 __attribute__((ext_vector_type(2)));
typedef float f32x2 __attribute__((ext_vector_type(2)));
typedef float f32x4 __attribute__((ext_vector_type(4)));

#define SEG_LOG 19
#define SEG_PTS (1 << SEG_LOG)   // 524288 points per output segment
#define NBIN 4096                // 64x64 uv bins
#define BLK_PTS 16384            // points per hist/scatter block (divides SEG_PTS)

__device__ __forceinline__ int binof(float u, float v) {
    int bx = (int)(u * 64.0f);
    int by = (int)(v * 64.0f);
    bx = min(max(bx, 0), 63);
    by = min(max(by, 0), 63);
    return by * 64 + bx;
}

// ---- repack (fused, all 4 levels) + zero the histogram counters ----
__global__ __launch_bounds__(256) void repack_all_kernel(
    const float* __restrict__ l1, const float* __restrict__ l2,
    const float* __restrict__ l3, const float* __restrict__ l4,
    __half2* __restrict__ r1, __half2* __restrict__ r2,
    __half2* __restrict__ r3, __half2* __restrict__ r4,
    unsigned* __restrict__ hist, int nzero) {
    const int n1 = 2048 * 2048, n2 = 1024 * 1024, n3 = 512 * 512, n4 = 256 * 256;
    int i = blockIdx.x * 256 + threadIdx.x;
    if (hist != nullptr && i < nzero) hist[i] = 0u;
    const float* __restrict__ src;
    __half2* __restrict__ dst;
    int S, logS, j;
    if (i < n1) {
        src = l1; dst = r1; S = 2048; logS = 11; j = i;
    } else if (i < n1 + n2) {
        src = l2; dst = r2; S = 1024; logS = 10; j = i - n1;
    } else if (i < n1 + n2 + n3) {
        src = l3; dst = r3; S = 512; logS = 9; j = i - (n1 + n2);
    } else if (i < n1 + n2 + n3 + n4) {
        src = l4; dst = r4; S = 256; logS = 8; j = i - (n1 + n2 + n3);
    } else {
        return;
    }
    int y = j >> logS;
    float a = src[j];
    float b = src[(y < S - 1) ? (j + S) : j];
    dst[j] = __halves2half2(__float2half(a), __float2half(b));
}

// ---- pass 1: per-segment histogram over 4096 bins (LDS-aggregated) ----
__global__ __launch_bounds__(256) void hist_kernel(
    const float2* __restrict__ uv, unsigned* __restrict__ hist, int n) {
    __shared__ unsigned lh[NBIN];
    for (int t = threadIdx.x; t < NBIN; t += 256) lh[t] = 0u;
    __syncthreads();
    int base = blockIdx.x * BLK_PTS;
    const f32x4* uv4 = (const f32x4*)uv;
    for (int k = 0; k < BLK_PTS / 512; ++k) {
        int p = base + k * 512 + threadIdx.x * 2;
        if (p + 1 < n) {
            f32x4 q = __builtin_nontemporal_load(&uv4[p >> 1]);
            atomicAdd(&lh[binof(q.x, q.y)], 1u);
            atomicAdd(&lh[binof(q.z, q.w)], 1u);
        } else if (p < n) {
            float2 q = uv[p];
            atomicAdd(&lh[binof(q.x, q.y)], 1u);
        }
    }
    __syncthreads();
    int seg = base >> SEG_LOG;
    unsigned* gh = hist + (size_t)seg * NBIN;
    for (int t = threadIdx.x; t < NBIN; t += 256) {
        unsigned v = lh[t];
        if (v) atomicAdd(&gh[t], v);
    }
}

// ---- pass 2: per-segment exclusive scan of 4096 bins -> global cursors ----
__global__ __launch_bounds__(256) void scan_kernel(
    const unsigned* __restrict__ hist, unsigned* __restrict__ cursor) {
    int seg = blockIdx.x;
    const unsigned* h = hist + (size_t)seg * NBIN;
    unsigned* c = cursor + (size_t)seg * NBIN;
    __shared__ unsigned part[256];
    int t = threadIdx.x;
    unsigned vals[16];
    unsigned s = 0;
    for (int j = 0; j < 16; ++j) {
        vals[j] = s;               // exclusive within this thread's 16 bins
        s += h[t * 16 + j];
    }
    part[t] = s;
    __syncthreads();
    for (int off = 1; off < 256; off <<= 1) {
        unsigned x = (t >= off) ? part[t - off] : 0u;
        __syncthreads();
        part[t] += x;
        __syncthreads();
    }
    unsigned tbase = (t > 0) ? part[t - 1] : 0u;
    unsigned segbase = (unsigned)(seg << SEG_LOG);
    for (int j = 0; j < 16; ++j) c[t * 16 + j] = segbase + tbase + vals[j];
}

// ---- pass 3: scatter points into bin-sorted order (block-aggregated cursors) ----
__global__ __launch_bounds__(256) void scatter_kernel(
    const float2* __restrict__ uv, unsigned* __restrict__ cursor,
    float2* __restrict__ uv_s, unsigned* __restrict__ idx_s, int n) {
    __shared__ unsigned lh[NBIN];
    for (int t = threadIdx.x; t < NBIN; t += 256) lh[t] = 0u;
    __syncthreads();
    int base = blockIdx.x * BLK_PTS;
    const f32x4* uv4 = (const f32x4*)uv;
    // phase A: block-local counts
    for (int k = 0; k < BLK_PTS / 512; ++k) {
        int p = base + k * 512 + threadIdx.x * 2;
        if (p + 1 < n) {
            f32x4 q = __builtin_nontemporal_load(&uv4[p >> 1]);
            atomicAdd(&lh[binof(q.x, q.y)], 1u);
            atomicAdd(&lh[binof(q.z, q.w)], 1u);
        } else if (p < n) {
            float2 q = uv[p];
            atomicAdd(&lh[binof(q.x, q.y)], 1u);
        }
    }
    __syncthreads();
    // phase B: reserve global ranges; lh[bin] becomes the running global cursor
    int seg = base >> SEG_LOG;
    unsigned* cur = cursor + (size_t)seg * NBIN;
    for (int t = threadIdx.x; t < NBIN; t += 256) {
        unsigned v = lh[t];
        unsigned b = v ? atomicAdd(&cur[t], v) : 0u;
        lh[t] = b;
    }
    __syncthreads();
    // phase C: emit records at reserved positions
    for (int k = 0; k < BLK_PTS / 512; ++k) {
        int p = base + k * 512 + threadIdx.x * 2;
        if (p + 1 < n) {
            f32x4 q = uv4[p >> 1];  // L2-hot re-read
            unsigned pos0 = atomicAdd(&lh[binof(q.x, q.y)], 1u);
            uv_s[pos0] = make_float2(q.x, q.y);
            idx_s[pos0] = (unsigned)p;
            unsigned pos1 = atomicAdd(&lh[binof(q.z, q.w)], 1u);
            uv_s[pos1] = make_float2(q.z, q.w);
            idx_s[pos1] = (unsigned)(p + 1);
        } else if (p < n) {
            float2 q = uv[p];
            unsigned pos0 = atomicAdd(&lh[binof(q.x, q.y)], 1u);
            uv_s[pos0] = q;
            idx_s[pos0] = (unsigned)p;
        }
    }
}

// ---- bilinear tap from row-pair half2 texture (memcpy path: cached loads) ----
__device__ __forceinline__ float sample_level(const __half2* __restrict__ R,
                                              const int S, const float gx,
                                              const float gy) {
    const float halfS = 0.5f * (float)S;
    float x = (gx + 1.0f) * halfS - 0.5f;
    float y = (gy + 1.0f) * halfS - 0.5f;
    float xf = floorf(x), yf = floorf(y);
    float wx = x - xf, wy = y - yf;
    int x0 = (int)xf, y0 = (int)yf;

    int yc = min(max(y0, 0), S - 1);
    float wa = (y0 >= 0) ? (1.0f - wy) : wy;
    if (y0 < -1 || y0 >= S) wa = 0.0f;  // defensive (outside expected domain)
    float wb = (y0 >= 0 && y0 < S - 1) ? wy : 0.0f;

    int xb = min(max(x0, 0), S - 2);
    bool xin = (x0 >= 0) && (x0 <= S - 2);
    float wxa = xin ? (1.0f - wx) : ((x0 == -1) ? wx : 0.0f);
    float wxb = xin ? wx : ((x0 == S - 1) ? (1.0f - wx) : 0.0f);

    uint2 q;
    __builtin_memcpy(&q, (const char*)(R + (size_t)yc * (size_t)S + xb), 8);
    __half2 ca = *(const __half2*)&q.x;  // (img[yc][xb],   img[yc+1][xb])
    __half2 cb = *(const __half2*)&q.y;  // (img[yc][xb+1], img[yc+1][xb+1])
    float2 fa = __half22float2(ca);
    float2 fb = __half22float2(cb);
    float cola = fmaf(wa, fa.x, wb * fa.y);
    float colb = fmaf(wa, fb.x, wb * fb.y);
    return fmaf(wxa, cola, wxb * colb);
}

__device__ __forceinline__ float sample_point(const __half2* __restrict__ r1,
                                              const __half2* __restrict__ r2,
                                              const __half2* __restrict__ r3,
                                              const __half2* __restrict__ r4,
                                              float ux, float uy) {
    float gx = ux * 2.0f - 1.0f;
    float gy = uy * 2.0f - 1.0f;
    float acc = sample_level(r1, 2048, gx, gy);
    acc += sample_level(r2, 1024, gx, gy);
    acc += sample_level(r3, 512, gx, gy);
    acc += sample_level(r4, 256, gx, gy);
    return acc;
}

// ---- pass 4: sample in sorted order, scatter to out (segment-local window) ----
__global__ __launch_bounds__(256) void lappyr_sample_sorted(
    const float2* __restrict__ uv_s, const unsigned* __restrict__ idx_s,
    const __half2* __restrict__ r1, const __half2* __restrict__ r2,
    const __half2* __restrict__ r3, const __half2* __restrict__ r4,
    float* __restrict__ out, int n) {
    int i = blockIdx.x * 256 + threadIdx.x;
    int p0 = i * 2;
    if (p0 >= n) return;
    if (p0 + 1 < n) {
        f32x4 q = __builtin_nontemporal_load((const f32x4*)uv_s + i);
        u32x2 id = __builtin_nontemporal_load((const u32x2*)idx_s + i);
        float a0 = sample_point(r1, r2, r3, r4, q.x, q.y);
        float a1 = sample_point(r1, r2, r3, r4, q.z, q.w);
        out[id.x] = a0;  // scatter stays inside one 2MB segment window
        out[id.y] = a1;
    } else {
        float2 q = uv_s[p0];
        out[idx_s[p0]] = sample_point(r1, r2, r3, r4, q.x, q.y);
    }
}

// ---- fallback A: unsorted sampling over repacked levels (round-0 baseline) ----
__global__ __launch_bounds__(256) void lappyr_sample_kernel(
    const float2* __restrict__ uv, const __half2* __restrict__ r1,
    const __half2* __restrict__ r2, const __half2* __restrict__ r3,
    const __half2* __restrict__ r4, float* __restrict__ out, int n) {
    int i = blockIdx.x * blockDim.x + threadIdx.x;
    if (i >= n) return;
    float2 p = uv[i];
    out[i] = sample_point(r1, r2, r3, r4, p.x, p.y);
}

// ---- fallback B (ws too small): direct f32 sampling ----
__device__ __forceinline__ float bilin_f32(const float* __restrict__ img,
                                           const int S, const float gx,
                                           const float gy) {
    const float halfS = 0.5f * (float)S;
    float x = (gx + 1.0f) * halfS - 0.5f;
    float y = (gy + 1.0f) * halfS - 0.5f;
    float xf = floorf(x), yf = floorf(y);
    float wx = x - xf, wy = y - yf;
    int x0 = (int)xf, y0 = (int)yf, x1 = x0 + 1, y1 = y0 + 1;
    float ex0 = (x0 >= 0 && x0 < S) ? (1.0f - wx) : 0.0f;
    float ex1 = (x1 >= 0 && x1 < S) ? wx : 0.0f;
    float ey0 = (y0 >= 0 && y0 < S) ? (1.0f - wy) : 0.0f;
    float ey1 = (y1 >= 0 && y1 < S) ? wy : 0.0f;
    int xc0 = min(max(x0, 0), S - 1), xc1 = min(max(x1, 0), S - 1);
    int yc0 = min(max(y0, 0), S - 1), yc1 = min(max(y1, 0), S - 1);
    const float* r0 = img + (size_t)yc0 * S;
    const float* r1 = img + (size_t)yc1 * S;
    return ey0 * fmaf(ex0, r0[xc0], ex1 * r0[xc1]) +
           ey1 * fmaf(ex0, r1[xc0], ex1 * r1[xc1]);
}

__global__ __launch_bounds__(256) void lappyr_f32_kernel(
    const float2* __restrict__ uv, const float* __restrict__ l1,
    const float* __restrict__ l2, const float* __restrict__ l3,
    const float* __restrict__ l4, float* __restrict__ out, int n) {
    int i = blockIdx.x * blockDim.x + threadIdx.x;
    if (i >= n) return;
    float2 p = uv[i];
    float gx = p.x * 2.0f - 1.0f;
    float gy = p.y * 2.0f - 1.0f;
    float acc = bilin_f32(l1, 2048, gx, gy);
    acc += bilin_f32(l2, 1024, gx, gy);
    acc += bilin_f32(l3, 512, gx, gy);
    acc += bilin_f32(l4, 256, gx, gy);
    out[i] = acc;
}

extern "C" void kernel_launch(void* const* d_in, const int* in_sizes, int n_in,
                              void* d_out, int out_size, void* d_ws, size_t ws_size,
                              hipStream_t stream) {
    const float2* uv = (const float2*)d_in[0];
    const float* l1 = (const float*)d_in[1];
    const float* l2 = (const float*)d_in[2];
    const float* l3 = (const float*)d_in[3];
    const float* l4 = (const float*)d_in[4];
    float* out = (float*)d_out;
    int n = out_size;

    const size_t n1 = 2048u * 2048u, n2 = 1024u * 1024u, n3 = 512u * 512u,
                 n4 = 256u * 256u;
    const size_t ntot = n1 + n2 + n3 + n4;
    const size_t rep_bytes = ntot * sizeof(__half2);  // ~21.25 MiB

    int nseg = (n + SEG_PTS - 1) >> SEG_LOG;
    size_t off_uvs = (rep_bytes + 255) & ~(size_t)255;
    size_t off_idx = off_uvs + (size_t)n * 8;
    size_t off_hist = (off_idx + (size_t)n * 4 + 255) & ~(size_t)255;
    size_t off_cur = off_hist + (size_t)nseg * NBIN * 4;
    size_t need_sort = off_cur + (size_t)nseg * NBIN * 4;

    if (ws_size >= rep_bytes) {
        char* ws = (char*)d_ws;
        __half2* r1 = (__half2*)ws;
        __half2* r2 = r1 + n1;
        __half2* r3 = r2 + n2;
        __half2* r4 = r3 + n3;
        bool do_sort = (ws_size >= need_sort);
        unsigned* hist = do_sort ? (unsigned*)(ws + off_hist) : nullptr;
        int nzero = do_sort ? nseg * NBIN : 0;
        repack_all_kernel<<<(int)((ntot + 255) / 256), 256, 0, stream>>>(
            l1, l2, l3, l4, r1, r2, r3, r4, hist, nzero);
        if (do_sort) {
            float2* uv_s = (float2*)(ws + off_uvs);
            unsigned* idx_s = (unsigned*)(ws + off_idx);
            unsigned* cursor = (unsigned*)(ws + off_cur);
            int nb = (n + BLK_PTS - 1) / BLK_PTS;
            hist_kernel<<<nb, 256, 0, stream>>>(uv, hist, n);
            scan_kernel<<<nseg, 256, 0, stream>>>(hist, cursor);
            scatter_kernel<<<nb, 256, 0, stream>>>(uv, cursor, uv_s, idx_s, n);
            int nh = (n + 1) / 2;
            lappyr_sample_sorted<<<(nh + 255) / 256, 256, 0, stream>>>(
                uv_s, idx_s, r1, r2, r3, r4, out, n);
        } else {
            lappyr_sample_kernel<<<(n + 255) / 256, 256, 0, stream>>>(
                uv, r1, r2, r3, r4, out, n);
        }
    } else {
        lappyr_f32_kernel<<<(n + 255) / 256, 256, 0, stream>>>(uv, l1, l2, l3, l4,
                                                               out, n);
    }
}

// Round 3
// 431.886 us; speedup vs baseline: 1.5223x; 1.5223x over previous
//
#include <hip/hip_runtime.h>
#include <hip/hip_fp16.h>

// Layout: per level, fp16 ROW-PAIR repack R[y][x] = half2(img[y][x], img[min(y+1,S-1)][x]).
// One bilinear quad = one 8-byte load, zero-padding folded into weights.
//
// Round 3: sort retained (round-2 proved correctness + sample-side win), but the
// record scatter is rebuilt as an LDS-staged reorder so ALL global record writes
// are short coalesced runs (round-2's random 12B writes caused 5x writeback
// amplification, 525MB @ 1.4TB/s = 377us). Kernel count cut to 3 (+memsetAsync):
// hist fused into repack; the 1024-bin segment scan is recomputed per partition
// block in LDS. Bins = 32x32 grid (64x64-texel tiles, all 4 levels = 21.25KB/bin
// -> L1-resident during sampling). Segments of ~2.1M pts keep out[idx] scatter in
// an 8MB L2-resident window.

typedef unsigned int u32x2 __attribute__((ext_vector_type(2)));
typedef float f32x4 __attribute__((ext_vector_type(4)));

#define K 1024            // 32x32 uv bins
#define CHUNK 6144        // points per partition block (LDS-staged)
#define HB 4096           // points per hist block (in repack kernel)
#define SEG (CHUNK * 342) // 2101248 pts/segment = 513*HB (both divide evenly)

__device__ __forceinline__ int binof(float u, float v) {
    int bx = min(max((int)(u * 32.0f), 0), 31);
    int by = min(max((int)(v * 32.0f), 0), 31);
    return by * 32 + bx;
}

// ---- kernel A: repack all 4 levels + per-segment 1024-bin histogram ----
__global__ __launch_bounds__(256) void repack_hist_kernel(
    const float* __restrict__ l1, const float* __restrict__ l2,
    const float* __restrict__ l3, const float* __restrict__ l4,
    __half2* __restrict__ r1, __half2* __restrict__ r2,
    __half2* __restrict__ r3, __half2* __restrict__ r4,
    const float2* __restrict__ uv, unsigned* __restrict__ hist, int n) {
    const int n1 = 2048 * 2048, n2 = 1024 * 1024, n3 = 512 * 512, n4 = 256 * 256;
    int i = blockIdx.x * 256 + threadIdx.x;
    // --- repack share ---
    {
        const float* __restrict__ src = nullptr;
        __half2* __restrict__ dst = nullptr;
        int S = 0, logS = 0, j = 0;
        if (i < n1) {
            src = l1; dst = r1; S = 2048; logS = 11; j = i;
        } else if (i < n1 + n2) {
            src = l2; dst = r2; S = 1024; logS = 10; j = i - n1;
        } else if (i < n1 + n2 + n3) {
            src = l3; dst = r3; S = 512; logS = 9; j = i - (n1 + n2);
        } else if (i < n1 + n2 + n3 + n4) {
            src = l4; dst = r4; S = 256; logS = 8; j = i - (n1 + n2 + n3);
        }
        if (src) {
            int y = j >> logS;
            float a = src[j];
            float b = src[(y < S - 1) ? (j + S) : j];
            dst[j] = __halves2half2(__float2half(a), __float2half(b));
        }
    }
    // --- histogram share (blocks 0 .. ceil(n/HB)-1) ---
    if (hist == nullptr) return;
    int base = blockIdx.x * HB;
    if (base >= n) return;
    __shared__ unsigned cnt[K];
    for (int b = threadIdx.x; b < K; b += 256) cnt[b] = 0u;
    __syncthreads();
    int m = min(HB, n - base);
    const f32x4* uv4 = (const f32x4*)(uv + base);
    int npair = m >> 1;
    for (int k2 = threadIdx.x; k2 < npair; k2 += 256) {
        f32x4 q = __builtin_nontemporal_load(&uv4[k2]);
        atomicAdd(&cnt[binof(q.x, q.y)], 1u);
        atomicAdd(&cnt[binof(q.z, q.w)], 1u);
    }
    if ((m & 1) && threadIdx.x == 0) {
        float2 q = uv[base + m - 1];
        atomicAdd(&cnt[binof(q.x, q.y)], 1u);
    }
    __syncthreads();
    int seg = base / SEG;
    unsigned* gh = hist + (size_t)seg * K;
    for (int b = threadIdx.x; b < K; b += 256) {
        unsigned v = cnt[b];
        if (v) atomicAdd(&gh[b], v);
    }
}

// ---- kernel B: partition -> bin-sorted records via LDS-staged reorder ----
__global__ __launch_bounds__(256) void partition_kernel(
    const float2* __restrict__ uv, const unsigned* __restrict__ hist,
    unsigned* __restrict__ cursor, float2* __restrict__ uv_s,
    unsigned* __restrict__ idx_s, int n) {
    __shared__ float2 suv[CHUNK];          // 48 KB
    __shared__ unsigned short slid[CHUNK]; // 12 KB
    __shared__ unsigned cnt[K];            // 4 KB
    __shared__ unsigned lbase[K];          // 4 KB
    __shared__ unsigned goff[K];           // 4 KB
    __shared__ unsigned part[256];         // 1 KB
    int t = threadIdx.x;
    int cb = blockIdx.x * CHUNK;
    if (cb >= n) return;
    int cnum = min(CHUNK, n - cb);
    int seg = cb / SEG;  // CHUNK divides SEG -> no straddle
    unsigned segstart = (unsigned)((size_t)seg * SEG);

    // load chunk into LDS (coalesced 16B)
    {
        const f32x4* uv4 = (const f32x4*)(uv + cb);
        int npair = cnum >> 1;
        for (int k2 = t; k2 < npair; k2 += 256) {
            f32x4 q = uv4[k2];
            suv[k2 * 2] = make_float2(q.x, q.y);
            suv[k2 * 2 + 1] = make_float2(q.z, q.w);
        }
        if ((cnum & 1) && t == 0) suv[cnum - 1] = uv[cb + cnum - 1];
    }
    for (int b = t; b < K; b += 256) cnt[b] = 0u;
    __syncthreads();
    // block-local bin counts
    for (int k = t; k < cnum; k += 256)
        atomicAdd(&cnt[binof(suv[k].x, suv[k].y)], 1u);
    __syncthreads();
    // exclusive scan of cnt -> lbase (4 bins/thread + Hillis-Steele on partials)
    {
        unsigned v0 = cnt[t * 4], v1 = cnt[t * 4 + 1], v2 = cnt[t * 4 + 2],
                 v3 = cnt[t * 4 + 3];
        unsigned s1 = v0, s2 = v0 + v1, s3 = v0 + v1 + v2;
        part[t] = s3 + v3;
        __syncthreads();
        for (int off = 1; off < 256; off <<= 1) {
            unsigned x = (t >= off) ? part[t - off] : 0u;
            __syncthreads();
            part[t] += x;
            __syncthreads();
        }
        unsigned tb = (t > 0) ? part[t - 1] : 0u;
        lbase[t * 4] = tb;
        lbase[t * 4 + 1] = tb + s1;
        lbase[t * 4 + 2] = tb + s2;
        lbase[t * 4 + 3] = tb + s3;
    }
    __syncthreads();
    // exclusive scan of this segment's hist -> sbase; reserve global ranges
    {
        const unsigned* h = hist + (size_t)seg * K;
        unsigned v0 = h[t * 4], v1 = h[t * 4 + 1], v2 = h[t * 4 + 2],
                 v3 = h[t * 4 + 3];
        unsigned s1 = v0, s2 = v0 + v1, s3 = v0 + v1 + v2;
        part[t] = s3 + v3;
        __syncthreads();
        for (int off = 1; off < 256; off <<= 1) {
            unsigned x = (t >= off) ? part[t - off] : 0u;
            __syncthreads();
            part[t] += x;
            __syncthreads();
        }
        unsigned tb = (t > 0) ? part[t - 1] : 0u;
        unsigned sb0 = tb, sb1 = tb + s1, sb2 = tb + s2, sb3 = tb + s3;
        unsigned sbv[4] = {sb0, sb1, sb2, sb3};
        for (int j = 0; j < 4; ++j) {
            int b = t * 4 + j;
            unsigned c = cnt[b];
            unsigned r = c ? atomicAdd(&cursor[(size_t)seg * K + b], c) : 0u;
            goff[b] = segstart + sbv[j] + r;
        }
    }
    __syncthreads();
    // zero cnt, then rank each point within its bin -> staging permutation
    for (int b = t; b < K; b += 256) cnt[b] = 0u;
    __syncthreads();
    for (int k = t; k < cnum; k += 256) {
        int b = binof(suv[k].x, suv[k].y);
        unsigned r = lbase[b] + atomicAdd(&cnt[b], 1u);
        slid[r] = (unsigned short)k;
    }
    __syncthreads();
    // emit in sorted order: global writes are per-bin runs (coalesced)
    for (int s = t; s < cnum; s += 256) {
        int lid = slid[s];
        float2 q = suv[lid];
        int b = binof(q.x, q.y);
        unsigned pos = goff[b] + ((unsigned)s - lbase[b]);
        uv_s[pos] = q;
        idx_s[pos] = (unsigned)(cb + lid);
    }
}

// ---- bilinear tap from row-pair half2 texture ----
__device__ __forceinline__ float sample_level(const __half2* __restrict__ R,
                                              const int S, const float gx,
                                              const float gy) {
    const float halfS = 0.5f * (float)S;
    float x = (gx + 1.0f) * halfS - 0.5f;
    float y = (gy + 1.0f) * halfS - 0.5f;
    float xf = floorf(x), yf = floorf(y);
    float wx = x - xf, wy = y - yf;
    int x0 = (int)xf, y0 = (int)yf;

    int yc = min(max(y0, 0), S - 1);
    float wa = (y0 >= 0) ? (1.0f - wy) : wy;
    if (y0 < -1 || y0 >= S) wa = 0.0f;
    float wb = (y0 >= 0 && y0 < S - 1) ? wy : 0.0f;

    int xb = min(max(x0, 0), S - 2);
    bool xin = (x0 >= 0) && (x0 <= S - 2);
    float wxa = xin ? (1.0f - wx) : ((x0 == -1) ? wx : 0.0f);
    float wxb = xin ? wx : ((x0 == S - 1) ? (1.0f - wx) : 0.0f);

    uint2 q;
    __builtin_memcpy(&q, (const char*)(R + (size_t)yc * (size_t)S + xb), 8);
    __half2 ca = *(const __half2*)&q.x;
    __half2 cb = *(const __half2*)&q.y;
    float2 fa = __half22float2(ca);
    float2 fb = __half22float2(cb);
    float cola = fmaf(wa, fa.x, wb * fa.y);
    float colb = fmaf(wa, fb.x, wb * fb.y);
    return fmaf(wxa, cola, wxb * colb);
}

__device__ __forceinline__ float sample_point(const __half2* __restrict__ r1,
                                              const __half2* __restrict__ r2,
                                              const __half2* __restrict__ r3,
                                              const __half2* __restrict__ r4,
                                              float ux, float uy) {
    float gx = ux * 2.0f - 1.0f;
    float gy = uy * 2.0f - 1.0f;
    float acc = sample_level(r1, 2048, gx, gy);
    acc += sample_level(r2, 1024, gx, gy);
    acc += sample_level(r3, 512, gx, gy);
    acc += sample_level(r4, 256, gx, gy);
    return acc;
}

// ---- kernel C: sample in sorted order, scatter to out (seg-local window) ----
__global__ __launch_bounds__(256) void lappyr_sample_sorted(
    const float2* __restrict__ uv_s, const unsigned* __restrict__ idx_s,
    const __half2* __restrict__ r1, const __half2* __restrict__ r2,
    const __half2* __restrict__ r3, const __half2* __restrict__ r4,
    float* __restrict__ out, int n) {
    int i = blockIdx.x * 256 + threadIdx.x;
    int p0 = i * 2;
    if (p0 >= n) return;
    if (p0 + 1 < n) {
        f32x4 q = __builtin_nontemporal_load((const f32x4*)uv_s + i);
        u32x2 id = __builtin_nontemporal_load((const u32x2*)idx_s + i);
        float a0 = sample_point(r1, r2, r3, r4, q.x, q.y);
        float a1 = sample_point(r1, r2, r3, r4, q.z, q.w);
        out[id.x] = a0;
        out[id.y] = a1;
    } else {
        float2 q = uv_s[p0];
        out[idx_s[p0]] = sample_point(r1, r2, r3, r4, q.x, q.y);
    }
}

// ---- fallback A: unsorted sampling over repacked levels (round-0 baseline) ----
__global__ __launch_bounds__(256) void lappyr_sample_kernel(
    const float2* __restrict__ uv, const __half2* __restrict__ r1,
    const __half2* __restrict__ r2, const __half2* __restrict__ r3,
    const __half2* __restrict__ r4, float* __restrict__ out, int n) {
    int i = blockIdx.x * blockDim.x + threadIdx.x;
    if (i >= n) return;
    float2 p = uv[i];
    out[i] = sample_point(r1, r2, r3, r4, p.x, p.y);
}

// ---- fallback B (ws too small): direct f32 sampling ----
__device__ __forceinline__ float bilin_f32(const float* __restrict__ img,
                                           const int S, const float gx,
                                           const float gy) {
    const float halfS = 0.5f * (float)S;
    float x = (gx + 1.0f) * halfS - 0.5f;
    float y = (gy + 1.0f) * halfS - 0.5f;
    float xf = floorf(x), yf = floorf(y);
    float wx = x - xf, wy = y - yf;
    int x0 = (int)xf, y0 = (int)yf, x1 = x0 + 1, y1 = y0 + 1;
    float ex0 = (x0 >= 0 && x0 < S) ? (1.0f - wx) : 0.0f;
    float ex1 = (x1 >= 0 && x1 < S) ? wx : 0.0f;
    float ey0 = (y0 >= 0 && y0 < S) ? (1.0f - wy) : 0.0f;
    float ey1 = (y1 >= 0 && y1 < S) ? wy : 0.0f;
    int xc0 = min(max(x0, 0), S - 1), xc1 = min(max(x1, 0), S - 1);
    int yc0 = min(max(y0, 0), S - 1), yc1 = min(max(y1, 0), S - 1);
    const float* r0 = img + (size_t)yc0 * S;
    const float* r1 = img + (size_t)yc1 * S;
    return ey0 * fmaf(ex0, r0[xc0], ex1 * r0[xc1]) +
           ey1 * fmaf(ex0, r1[xc0], ex1 * r1[xc1]);
}

__global__ __launch_bounds__(256) void lappyr_f32_kernel(
    const float2* __restrict__ uv, const float* __restrict__ l1,
    const float* __restrict__ l2, const float* __restrict__ l3,
    const float* __restrict__ l4, float* __restrict__ out, int n) {
    int i = blockIdx.x * blockDim.x + threadIdx.x;
    if (i >= n) return;
    float2 p = uv[i];
    float gx = p.x * 2.0f - 1.0f;
    float gy = p.y * 2.0f - 1.0f;
    float acc = bilin_f32(l1, 2048, gx, gy);
    acc += bilin_f32(l2, 1024, gx, gy);
    acc += bilin_f32(l3, 512, gx, gy);
    acc += bilin_f32(l4, 256, gx, gy);
    out[i] = acc;
}

extern "C" void kernel_launch(void* const* d_in, const int* in_sizes, int n_in,
                              void* d_out, int out_size, void* d_ws, size_t ws_size,
                              hipStream_t stream) {
    const float2* uv = (const float2*)d_in[0];
    const float* l1 = (const float*)d_in[1];
    const float* l2 = (const float*)d_in[2];
    const float* l3 = (const float*)d_in[3];
    const float* l4 = (const float*)d_in[4];
    float* out = (float*)d_out;
    int n = out_size;

    const size_t n1 = 2048u * 2048u, n2 = 1024u * 1024u, n3 = 512u * 512u,
                 n4 = 256u * 256u;
    const size_t ntot = n1 + n2 + n3 + n4;
    const size_t rep_bytes = ntot * sizeof(__half2);  // ~21.25 MiB

    int nseg = (n + SEG - 1) / SEG;
    size_t off_uvs = (rep_bytes + 255) & ~(size_t)255;
    size_t off_idx = off_uvs + (size_t)n * 8;
    size_t off_hist = (off_idx + (size_t)n * 4 + 255) & ~(size_t)255;
    size_t off_cur = off_hist + (size_t)nseg * K * 4;
    size_t need_sort = off_cur + (size_t)nseg * K * 4;

    int repack_blocks = (int)((ntot + 255) / 256);

    if (ws_size >= rep_bytes) {
        char* ws = (char*)d_ws;
        __half2* r1 = (__half2*)ws;
        __half2* r2 = r1 + n1;
        __half2* r3 = r2 + n2;
        __half2* r4 = r3 + n3;
        bool do_sort = (ws_size >= need_sort) && (n > 0);
        if (do_sort) {
            float2* uv_s = (float2*)(ws + off_uvs);
            unsigned* idx_s = (unsigned*)(ws + off_idx);
            unsigned* hist = (unsigned*)(ws + off_hist);
            // zero hist + cursor (contiguous)
            hipMemsetAsync(ws + off_hist, 0, (size_t)nseg * K * 4 * 2, stream);
            int hist_blocks = (n + HB - 1) / HB;
            int ga = max(repack_blocks, hist_blocks);
            repack_hist_kernel<<<ga, 256, 0, stream>>>(l1, l2, l3, l4, r1, r2, r3,
                                                       r4, uv, hist, n);
            unsigned* cursor = (unsigned*)(ws + off_cur);
            int nchunks = (n + CHUNK - 1) / CHUNK;
            partition_kernel<<<nchunks, 256, 0, stream>>>(uv, hist, cursor, uv_s,
                                                          idx_s, n);
            int nh = (n + 1) / 2;
            lappyr_sample_sorted<<<(nh + 255) / 256, 256, 0, stream>>>(
                uv_s, idx_s, r1, r2, r3, r4, out, n);
        } else {
            repack_hist_kernel<<<repack_blocks, 256, 0, stream>>>(
                l1, l2, l3, l4, r1, r2, r3, r4, uv, nullptr, n);
            lappyr_sample_kernel<<<(n + 255) / 256, 256, 0, stream>>>(
                uv, r1, r2, r3, r4, out, n);
        }
    } else {
        lappyr_f32_kernel<<<(n + 255) / 256, 256, 0, stream>>>(uv, l1, l2, l3, l4,
                                                               out, n);
    }
}

// Round 4
// 361.100 us; speedup vs baseline: 1.8207x; 1.1960x over previous
//
#include <hip/hip_runtime.h>
#include <hip/hip_fp16.h>

// Layout: per level, fp16 ROW-PAIR repack R[y][x] = half2(img[y][x], img[min(y+1,S-1)][x]).
// One bilinear quad = one 8-byte load, zero-padding folded into weights.
//
// Round 4: round-3 counters showed the out[idx] scatter suffers 8.8x write
// amplification (WRITE_SIZE 295MB for a 33.5MB output): the scatter window is
// dirtied by CUs on all 8 XCDs -> each 64B line partially written back ~8x from
// non-coherent per-XCD L2s. Fix: XCD-PIN the work. SEG = 1M points (out window
// = 4MB = one XCD L2); blocks are remapped so segment s is processed only by
// blocks with blockIdx%8==s (consecutive blockIdx round-robin across XCDs).
// Same pinning for partition record writes. CHUNK 6144->4096 so SEG=256*CHUNK
// divides exactly (also drops partition LDS to ~53KB -> 3 blocks/CU).

typedef unsigned int u32x2 __attribute__((ext_vector_type(2)));
typedef float f32x4 __attribute__((ext_vector_type(4)));

#define K 1024                 // 32x32 uv bins
#define CHUNK 4096             // points per partition block (LDS-staged)
#define HB 4096                // points per hist block (in repack kernel)
#define SEG (CHUNK * 256)      // 1048576 pts/segment = 256 chunks = 256 hist blocks
#define NXCD 8

__device__ __forceinline__ int binof(float u, float v) {
    int bx = min(max((int)(u * 32.0f), 0), 31);
    int by = min(max((int)(v * 32.0f), 0), 31);
    return by * 32 + bx;
}

// ---- kernel A: repack all 4 levels + per-segment 1024-bin histogram ----
__global__ __launch_bounds__(256) void repack_hist_kernel(
    const float* __restrict__ l1, const float* __restrict__ l2,
    const float* __restrict__ l3, const float* __restrict__ l4,
    __half2* __restrict__ r1, __half2* __restrict__ r2,
    __half2* __restrict__ r3, __half2* __restrict__ r4,
    const float2* __restrict__ uv, unsigned* __restrict__ hist, int n) {
    const int n1 = 2048 * 2048, n2 = 1024 * 1024, n3 = 512 * 512, n4 = 256 * 256;
    int i = blockIdx.x * 256 + threadIdx.x;
    // --- repack share ---
    {
        const float* __restrict__ src = nullptr;
        __half2* __restrict__ dst = nullptr;
        int S = 0, logS = 0, j = 0;
        if (i < n1) {
            src = l1; dst = r1; S = 2048; logS = 11; j = i;
        } else if (i < n1 + n2) {
            src = l2; dst = r2; S = 1024; logS = 10; j = i - n1;
        } else if (i < n1 + n2 + n3) {
            src = l3; dst = r3; S = 512; logS = 9; j = i - (n1 + n2);
        } else if (i < n1 + n2 + n3 + n4) {
            src = l4; dst = r4; S = 256; logS = 8; j = i - (n1 + n2 + n3);
        }
        if (src) {
            int y = j >> logS;
            float a = src[j];
            float b = src[(y < S - 1) ? (j + S) : j];
            dst[j] = __halves2half2(__float2half(a), __float2half(b));
        }
    }
    // --- histogram share (blocks 0 .. ceil(n/HB)-1; HB divides SEG) ---
    if (hist == nullptr) return;
    int base = blockIdx.x * HB;
    if (base >= n) return;
    __shared__ unsigned cnt[K];
    for (int b = threadIdx.x; b < K; b += 256) cnt[b] = 0u;
    __syncthreads();
    int m = min(HB, n - base);
    const f32x4* uv4 = (const f32x4*)(uv + base);
    int npair = m >> 1;
    for (int k2 = threadIdx.x; k2 < npair; k2 += 256) {
        f32x4 q = __builtin_nontemporal_load(&uv4[k2]);
        atomicAdd(&cnt[binof(q.x, q.y)], 1u);
        atomicAdd(&cnt[binof(q.z, q.w)], 1u);
    }
    if ((m & 1) && threadIdx.x == 0) {
        float2 q = uv[base + m - 1];
        atomicAdd(&cnt[binof(q.x, q.y)], 1u);
    }
    __syncthreads();
    int seg = base / SEG;
    unsigned* gh = hist + (size_t)seg * K;
    for (int b = threadIdx.x; b < K; b += 256) {
        unsigned v = cnt[b];
        if (v) atomicAdd(&gh[b], v);
    }
}

// ---- kernel B: partition -> bin-sorted records via LDS-staged reorder ----
__global__ __launch_bounds__(256) void partition_kernel(
    const float2* __restrict__ uv, const unsigned* __restrict__ hist,
    unsigned* __restrict__ cursor, float2* __restrict__ uv_s,
    unsigned* __restrict__ idx_s, int n, int pinned) {
    __shared__ float2 suv[CHUNK];          // 32 KB
    __shared__ unsigned short slid[CHUNK]; // 8 KB
    __shared__ unsigned cnt[K];            // 4 KB
    __shared__ unsigned lbase[K];          // 4 KB
    __shared__ unsigned goff[K];           // 4 KB
    __shared__ unsigned part[256];         // 1 KB
    int t = threadIdx.x;
    // XCD pinning: when n == 8*SEG there are exactly 2048 chunks; chunk
    // (x*256 + j) belongs to segment x and runs on a block with blockIdx%8==x.
    int blk = blockIdx.x;
    int c = pinned ? ((blk % NXCD) * (SEG / CHUNK) + blk / NXCD) : blk;
    int cb = c * CHUNK;
    if (cb >= n) return;
    int cnum = min(CHUNK, n - cb);
    int seg = cb / SEG;  // CHUNK divides SEG -> no straddle
    unsigned segstart = (unsigned)((size_t)seg * SEG);

    // load chunk into LDS (coalesced 16B)
    {
        const f32x4* uv4 = (const f32x4*)(uv + cb);
        int npair = cnum >> 1;
        for (int k2 = t; k2 < npair; k2 += 256) {
            f32x4 q = uv4[k2];
            suv[k2 * 2] = make_float2(q.x, q.y);
            suv[k2 * 2 + 1] = make_float2(q.z, q.w);
        }
        if ((cnum & 1) && t == 0) suv[cnum - 1] = uv[cb + cnum - 1];
    }
    for (int b = t; b < K; b += 256) cnt[b] = 0u;
    __syncthreads();
    // block-local bin counts
    for (int k = t; k < cnum; k += 256)
        atomicAdd(&cnt[binof(suv[k].x, suv[k].y)], 1u);
    __syncthreads();
    // exclusive scan of cnt -> lbase (4 bins/thread + Hillis-Steele on partials)
    {
        unsigned v0 = cnt[t * 4], v1 = cnt[t * 4 + 1], v2 = cnt[t * 4 + 2],
                 v3 = cnt[t * 4 + 3];
        unsigned s1 = v0, s2 = v0 + v1, s3 = v0 + v1 + v2;
        part[t] = s3 + v3;
        __syncthreads();
        for (int off = 1; off < 256; off <<= 1) {
            unsigned x = (t >= off) ? part[t - off] : 0u;
            __syncthreads();
            part[t] += x;
            __syncthreads();
        }
        unsigned tb = (t > 0) ? part[t - 1] : 0u;
        lbase[t * 4] = tb;
        lbase[t * 4 + 1] = tb + s1;
        lbase[t * 4 + 2] = tb + s2;
        lbase[t * 4 + 3] = tb + s3;
    }
    __syncthreads();
    // exclusive scan of this segment's hist -> reserve global ranges
    {
        const unsigned* h = hist + (size_t)seg * K;
        unsigned v0 = h[t * 4], v1 = h[t * 4 + 1], v2 = h[t * 4 + 2],
                 v3 = h[t * 4 + 3];
        unsigned s1 = v0, s2 = v0 + v1, s3 = v0 + v1 + v2;
        part[t] = s3 + v3;
        __syncthreads();
        for (int off = 1; off < 256; off <<= 1) {
            unsigned x = (t >= off) ? part[t - off] : 0u;
            __syncthreads();
            part[t] += x;
            __syncthreads();
        }
        unsigned tb = (t > 0) ? part[t - 1] : 0u;
        unsigned sbv[4] = {tb, tb + s1, tb + s2, tb + s3};
        for (int j = 0; j < 4; ++j) {
            int b = t * 4 + j;
            unsigned cc = cnt[b];
            unsigned r = cc ? atomicAdd(&cursor[(size_t)seg * K + b], cc) : 0u;
            goff[b] = segstart + sbv[j] + r;
        }
    }
    __syncthreads();
    // zero cnt, then rank each point within its bin -> staging permutation
    for (int b = t; b < K; b += 256) cnt[b] = 0u;
    __syncthreads();
    for (int k = t; k < cnum; k += 256) {
        int b = binof(suv[k].x, suv[k].y);
        unsigned r = lbase[b] + atomicAdd(&cnt[b], 1u);
        slid[r] = (unsigned short)k;
    }
    __syncthreads();
    // emit in sorted order: global writes are per-bin runs (coalesced)
    for (int s = t; s < cnum; s += 256) {
        int lid = slid[s];
        float2 q = suv[lid];
        int b = binof(q.x, q.y);
        unsigned pos = goff[b] + ((unsigned)s - lbase[b]);
        uv_s[pos] = q;
        idx_s[pos] = (unsigned)(cb + lid);
    }
}

// ---- bilinear tap from row-pair half2 texture ----
__device__ __forceinline__ float sample_level(const __half2* __restrict__ R,
                                              const int S, const float gx,
                                              const float gy) {
    const float halfS = 0.5f * (float)S;
    float x = (gx + 1.0f) * halfS - 0.5f;
    float y = (gy + 1.0f) * halfS - 0.5f;
    float xf = floorf(x), yf = floorf(y);
    float wx = x - xf, wy = y - yf;
    int x0 = (int)xf, y0 = (int)yf;

    int yc = min(max(y0, 0), S - 1);
    float wa = (y0 >= 0) ? (1.0f - wy) : wy;
    if (y0 < -1 || y0 >= S) wa = 0.0f;
    float wb = (y0 >= 0 && y0 < S - 1) ? wy : 0.0f;

    int xb = min(max(x0, 0), S - 2);
    bool xin = (x0 >= 0) && (x0 <= S - 2);
    float wxa = xin ? (1.0f - wx) : ((x0 == -1) ? wx : 0.0f);
    float wxb = xin ? wx : ((x0 == S - 1) ? (1.0f - wx) : 0.0f);

    uint2 q;
    __builtin_memcpy(&q, (const char*)(R + (size_t)yc * (size_t)S + xb), 8);
    __half2 ca = *(const __half2*)&q.x;
    __half2 cb = *(const __half2*)&q.y;
    float2 fa = __half22float2(ca);
    float2 fb = __half22float2(cb);
    float cola = fmaf(wa, fa.x, wb * fa.y);
    float colb = fmaf(wa, fb.x, wb * fb.y);
    return fmaf(wxa, cola, wxb * colb);
}

__device__ __forceinline__ float sample_point(const __half2* __restrict__ r1,
                                              const __half2* __restrict__ r2,
                                              const __half2* __restrict__ r3,
                                              const __half2* __restrict__ r4,
                                              float ux, float uy) {
    float gx = ux * 2.0f - 1.0f;
    float gy = uy * 2.0f - 1.0f;
    float acc = sample_level(r1, 2048, gx, gy);
    acc += sample_level(r2, 1024, gx, gy);
    acc += sample_level(r3, 512, gx, gy);
    acc += sample_level(r4, 256, gx, gy);
    return acc;
}

// ---- kernel C: sample in sorted order, scatter to out (XCD-pinned segment) ----
__global__ __launch_bounds__(256) void lappyr_sample_sorted(
    const float2* __restrict__ uv_s, const unsigned* __restrict__ idx_s,
    const __half2* __restrict__ r1, const __half2* __restrict__ r2,
    const __half2* __restrict__ r3, const __half2* __restrict__ r4,
    float* __restrict__ out, int n, int pinned) {
    // XCD pinning: block covers 512 sorted points; when n == 8*SEG the grid is
    // exactly 8 * (SEG/512); segment x runs on blocks with blockIdx%8==x so
    // out-scatter lines are dirtied by ONE XCD's L2 only.
    int blk = blockIdx.x;
    int sb = pinned ? ((blk % NXCD) * (SEG / 512) + blk / NXCD) : blk;
    int i = sb * 256 + threadIdx.x;
    int p0 = i * 2;
    if (p0 >= n) return;
    if (p0 + 1 < n) {
        f32x4 q = __builtin_nontemporal_load((const f32x4*)uv_s + i);
        u32x2 id = __builtin_nontemporal_load((const u32x2*)idx_s + i);
        float a0 = sample_point(r1, r2, r3, r4, q.x, q.y);
        float a1 = sample_point(r1, r2, r3, r4, q.z, q.w);
        out[id.x] = a0;  // cached store: line accumulates full coverage in-XCD
        out[id.y] = a1;
    } else {
        float2 q = uv_s[p0];
        out[idx_s[p0]] = sample_point(r1, r2, r3, r4, q.x, q.y);
    }
}

// ---- fallback A: unsorted sampling over repacked levels ----
__global__ __launch_bounds__(256) void lappyr_sample_kernel(
    const float2* __restrict__ uv, const __half2* __restrict__ r1,
    const __half2* __restrict__ r2, const __half2* __restrict__ r3,
    const __half2* __restrict__ r4, float* __restrict__ out, int n) {
    int i = blockIdx.x * blockDim.x + threadIdx.x;
    if (i >= n) return;
    float2 p = uv[i];
    out[i] = sample_point(r1, r2, r3, r4, p.x, p.y);
}

// ---- fallback B (ws too small): direct f32 sampling ----
__device__ __forceinline__ float bilin_f32(const float* __restrict__ img,
                                           const int S, const float gx,
                                           const float gy) {
    const float halfS = 0.5f * (float)S;
    float x = (gx + 1.0f) * halfS - 0.5f;
    float y = (gy + 1.0f) * halfS - 0.5f;
    float xf = floorf(x), yf = floorf(y);
    float wx = x - xf, wy = y - yf;
    int x0 = (int)xf, y0 = (int)yf, x1 = x0 + 1, y1 = y0 + 1;
    float ex0 = (x0 >= 0 && x0 < S) ? (1.0f - wx) : 0.0f;
    float ex1 = (x1 >= 0 && x1 < S) ? wx : 0.0f;
    float ey0 = (y0 >= 0 && y0 < S) ? (1.0f - wy) : 0.0f;
    float ey1 = (y1 >= 0 && y1 < S) ? wy : 0.0f;
    int xc0 = min(max(x0, 0), S - 1), xc1 = min(max(x1, 0), S - 1);
    int yc0 = min(max(y0, 0), S - 1), yc1 = min(max(y1, 0), S - 1);
    const float* r0 = img + (size_t)yc0 * S;
    const float* r1 = img + (size_t)yc1 * S;
    return ey0 * fmaf(ex0, r0[xc0], ex1 * r0[xc1]) +
           ey1 * fmaf(ex0, r1[xc0], ex1 * r1[xc1]);
}

__global__ __launch_bounds__(256) void lappyr_f32_kernel(
    const float2* __restrict__ uv, const float* __restrict__ l1,
    const float* __restrict__ l2, const float* __restrict__ l3,
    const float* __restrict__ l4, float* __restrict__ out, int n) {
    int i = blockIdx.x * blockDim.x + threadIdx.x;
    if (i >= n) return;
    float2 p = uv[i];
    float gx = p.x * 2.0f - 1.0f;
    float gy = p.y * 2.0f - 1.0f;
    float acc = bilin_f32(l1, 2048, gx, gy);
    acc += bilin_f32(l2, 1024, gx, gy);
    acc += bilin_f32(l3, 512, gx, gy);
    acc += bilin_f32(l4, 256, gx, gy);
    out[i] = acc;
}

extern "C" void kernel_launch(void* const* d_in, const int* in_sizes, int n_in,
                              void* d_out, int out_size, void* d_ws, size_t ws_size,
                              hipStream_t stream) {
    const float2* uv = (const float2*)d_in[0];
    const float* l1 = (const float*)d_in[1];
    const float* l2 = (const float*)d_in[2];
    const float* l3 = (const float*)d_in[3];
    const float* l4 = (const float*)d_in[4];
    float* out = (float*)d_out;
    int n = out_size;

    const size_t n1 = 2048u * 2048u, n2 = 1024u * 1024u, n3 = 512u * 512u,
                 n4 = 256u * 256u;
    const size_t ntot = n1 + n2 + n3 + n4;
    const size_t rep_bytes = ntot * sizeof(__half2);  // ~21.25 MiB

    int nseg = (n + SEG - 1) / SEG;
    size_t off_uvs = (rep_bytes + 255) & ~(size_t)255;
    size_t off_idx = off_uvs + (size_t)n * 8;
    size_t off_hist = (off_idx + (size_t)n * 4 + 255) & ~(size_t)255;
    size_t off_cur = off_hist + (size_t)nseg * K * 4;
    size_t need_sort = off_cur + (size_t)nseg * K * 4;

    int repack_blocks = (int)((ntot + 255) / 256);

    if (ws_size >= rep_bytes) {
        char* ws = (char*)d_ws;
        __half2* r1 = (__half2*)ws;
        __half2* r2 = r1 + n1;
        __half2* r3 = r2 + n2;
        __half2* r4 = r3 + n3;
        bool do_sort = (ws_size >= need_sort) && (n > 0);
        if (do_sort) {
            float2* uv_s = (float2*)(ws + off_uvs);
            unsigned* idx_s = (unsigned*)(ws + off_idx);
            unsigned* hist = (unsigned*)(ws + off_hist);
            unsigned* cursor = (unsigned*)(ws + off_cur);
            // exact-fit pinning: 8 segments, everything divides
            int pinned = (n == NXCD * SEG) ? 1 : 0;
            hipMemsetAsync(ws + off_hist, 0, (size_t)nseg * K * 4 * 2, stream);
            int hist_blocks = (n + HB - 1) / HB;
            int ga = max(repack_blocks, hist_blocks);
            repack_hist_kernel<<<ga, 256, 0, stream>>>(l1, l2, l3, l4, r1, r2, r3,
                                                       r4, uv, hist, n);
            int nchunks = (n + CHUNK - 1) / CHUNK;
            partition_kernel<<<nchunks, 256, 0, stream>>>(uv, hist, cursor, uv_s,
                                                          idx_s, n, pinned);
            int nh = (n + 1) / 2;
            lappyr_sample_sorted<<<(nh + 255) / 256, 256, 0, stream>>>(
                uv_s, idx_s, r1, r2, r3, r4, out, n, pinned);
        } else {
            repack_hist_kernel<<<repack_blocks, 256, 0, stream>>>(
                l1, l2, l3, l4, r1, r2, r3, r4, uv, nullptr, n);
            lappyr_sample_kernel<<<(n + 255) / 256, 256, 0, stream>>>(
                uv, r1, r2, r3, r4, out, n);
        }
    } else {
        lappyr_f32_kernel<<<(n + 255) / 256, 256, 0, stream>>>(uv, l1, l2, l3, l4,
                                                               out, n);
    }
}

// Round 5
// 312.463 us; speedup vs baseline: 2.1042x; 1.1557x over previous
//
#include <hip/hip_runtime.h>
#include <hip/hip_fp16.h>

// Layout: per level, fp16 ROW-PAIR repack R[y][x] = half2(img[y][x], img[min(y+1,S-1)][x]).
// One bilinear quad = one 8-byte load, zero-padding folded into weights.
//
// Round 5: round-4 showed the out[idx] scatter's WRITE amplification (365MB for
// 33.5MB payload) is structural: random 4B stores across a 4MB window live for
// the whole kernel can't stay L2-resident. Fix: INVERT the permutation.
//  - partition writes inv[p]=sorted_pos (coalesced; rank atomic gives pos)
//  - sample writes val_s[pos] coalesced (no scatter, no idx read)
//  - new unsort kernel: out[p] = val_s[inv[p]] -- the randomness moves to READS
//    (no writeback/RFO amplification; val_s is L3-resident, segment window is
//    XCD-pinned L2). All streams NT except val_s.
// 4 pts/thread in sample/unsort. Middle fallback = round-4 pipeline (361us),
// then unsorted repack path, then f32 path.

typedef unsigned int u32x2 __attribute__((ext_vector_type(2)));
typedef unsigned int u32x4 __attribute__((ext_vector_type(4)));
typedef float f32x4 __attribute__((ext_vector_type(4)));

#define K 1024                 // 32x32 uv bins
#define CHUNK 4096             // points per partition block (LDS-staged)
#define HB 4096                // points per hist block (in repack kernel)
#define SEG (CHUNK * 256)      // 1048576 pts/segment
#define NXCD 8

__device__ __forceinline__ int binof(float u, float v) {
    int bx = min(max((int)(u * 32.0f), 0), 31);
    int by = min(max((int)(v * 32.0f), 0), 31);
    return by * 32 + bx;
}

// ---- kernel A: repack all 4 levels + per-segment 1024-bin histogram ----
__global__ __launch_bounds__(256) void repack_hist_kernel(
    const float* __restrict__ l1, const float* __restrict__ l2,
    const float* __restrict__ l3, const float* __restrict__ l4,
    __half2* __restrict__ r1, __half2* __restrict__ r2,
    __half2* __restrict__ r3, __half2* __restrict__ r4,
    const float2* __restrict__ uv, unsigned* __restrict__ hist, int n) {
    const int n1 = 2048 * 2048, n2 = 1024 * 1024, n3 = 512 * 512, n4 = 256 * 256;
    int i = blockIdx.x * 256 + threadIdx.x;
    {
        const float* __restrict__ src = nullptr;
        __half2* __restrict__ dst = nullptr;
        int S = 0, logS = 0, j = 0;
        if (i < n1) {
            src = l1; dst = r1; S = 2048; logS = 11; j = i;
        } else if (i < n1 + n2) {
            src = l2; dst = r2; S = 1024; logS = 10; j = i - n1;
        } else if (i < n1 + n2 + n3) {
            src = l3; dst = r3; S = 512; logS = 9; j = i - (n1 + n2);
        } else if (i < n1 + n2 + n3 + n4) {
            src = l4; dst = r4; S = 256; logS = 8; j = i - (n1 + n2 + n3);
        }
        if (src) {
            int y = j >> logS;
            float a = src[j];
            float b = src[(y < S - 1) ? (j + S) : j];
            dst[j] = __halves2half2(__float2half(a), __float2half(b));
        }
    }
    if (hist == nullptr) return;
    int base = blockIdx.x * HB;
    if (base >= n) return;
    __shared__ unsigned cnt[K];
    for (int b = threadIdx.x; b < K; b += 256) cnt[b] = 0u;
    __syncthreads();
    int m = min(HB, n - base);
    const f32x4* uv4 = (const f32x4*)(uv + base);
    int npair = m >> 1;
    for (int k2 = threadIdx.x; k2 < npair; k2 += 256) {
        f32x4 q = __builtin_nontemporal_load(&uv4[k2]);
        atomicAdd(&cnt[binof(q.x, q.y)], 1u);
        atomicAdd(&cnt[binof(q.z, q.w)], 1u);
    }
    if ((m & 1) && threadIdx.x == 0) {
        float2 q = uv[base + m - 1];
        atomicAdd(&cnt[binof(q.x, q.y)], 1u);
    }
    __syncthreads();
    int seg = base / SEG;
    unsigned* gh = hist + (size_t)seg * K;
    for (int b = threadIdx.x; b < K; b += 256) {
        unsigned v = cnt[b];
        if (v) atomicAdd(&gh[b], v);
    }
}

// ---- kernel B: partition -> bin-sorted uv records + inverse permutation ----
__global__ __launch_bounds__(256) void partition_kernel(
    const float2* __restrict__ uv, const unsigned* __restrict__ hist,
    unsigned* __restrict__ cursor, float2* __restrict__ uv_s,
    unsigned* __restrict__ invp, unsigned* __restrict__ idxp, int n,
    int pinned) {
    __shared__ float2 suv[CHUNK];          // 32 KB
    __shared__ unsigned short slid[CHUNK]; // 8 KB
    __shared__ unsigned cnt[K];            // 4 KB
    __shared__ unsigned lbase[K];          // 4 KB
    __shared__ unsigned goff[K];           // 4 KB
    __shared__ unsigned part[256];         // 1 KB
    int t = threadIdx.x;
    int blk = blockIdx.x;
    int c = pinned ? ((blk % NXCD) * (SEG / CHUNK) + blk / NXCD) : blk;
    int cb = c * CHUNK;
    if (cb >= n) return;
    int cnum = min(CHUNK, n - cb);
    int seg = cb / SEG;  // CHUNK divides SEG -> no straddle
    unsigned segstart = (unsigned)((size_t)seg * SEG);

    {
        const f32x4* uv4 = (const f32x4*)(uv + cb);
        int npair = cnum >> 1;
        for (int k2 = t; k2 < npair; k2 += 256) {
            f32x4 q = uv4[k2];
            suv[k2 * 2] = make_float2(q.x, q.y);
            suv[k2 * 2 + 1] = make_float2(q.z, q.w);
        }
        if ((cnum & 1) && t == 0) suv[cnum - 1] = uv[cb + cnum - 1];
    }
    for (int b = t; b < K; b += 256) cnt[b] = 0u;
    __syncthreads();
    for (int k = t; k < cnum; k += 256)
        atomicAdd(&cnt[binof(suv[k].x, suv[k].y)], 1u);
    __syncthreads();
    // exclusive scan of cnt -> lbase
    {
        unsigned v0 = cnt[t * 4], v1 = cnt[t * 4 + 1], v2 = cnt[t * 4 + 2],
                 v3 = cnt[t * 4 + 3];
        unsigned s1 = v0, s2 = v0 + v1, s3 = v0 + v1 + v2;
        part[t] = s3 + v3;
        __syncthreads();
        for (int off = 1; off < 256; off <<= 1) {
            unsigned x = (t >= off) ? part[t - off] : 0u;
            __syncthreads();
            part[t] += x;
            __syncthreads();
        }
        unsigned tb = (t > 0) ? part[t - 1] : 0u;
        lbase[t * 4] = tb;
        lbase[t * 4 + 1] = tb + s1;
        lbase[t * 4 + 2] = tb + s2;
        lbase[t * 4 + 3] = tb + s3;
    }
    __syncthreads();
    // exclusive scan of this segment's hist -> reserve global ranges
    {
        const unsigned* h = hist + (size_t)seg * K;
        unsigned v0 = h[t * 4], v1 = h[t * 4 + 1], v2 = h[t * 4 + 2],
                 v3 = h[t * 4 + 3];
        unsigned s1 = v0, s2 = v0 + v1, s3 = v0 + v1 + v2;
        part[t] = s3 + v3;
        __syncthreads();
        for (int off = 1; off < 256; off <<= 1) {
            unsigned x = (t >= off) ? part[t - off] : 0u;
            __syncthreads();
            part[t] += x;
            __syncthreads();
        }
        unsigned tb = (t > 0) ? part[t - 1] : 0u;
        unsigned sbv[4] = {tb, tb + s1, tb + s2, tb + s3};
        for (int j = 0; j < 4; ++j) {
            int b = t * 4 + j;
            unsigned cc = cnt[b];
            unsigned r = cc ? atomicAdd(&cursor[(size_t)seg * K + b], cc) : 0u;
            goff[b] = segstart + sbv[j] + r;
        }
    }
    __syncthreads();
    for (int b = t; b < K; b += 256) cnt[b] = 0u;
    __syncthreads();
    // rank pass: permutation + (optionally) inverse permutation, coalesced in p
    for (int k = t; k < cnum; k += 256) {
        int b = binof(suv[k].x, suv[k].y);
        unsigned r = atomicAdd(&cnt[b], 1u);
        slid[lbase[b] + r] = (unsigned short)k;
        if (invp) invp[cb + k] = goff[b] + r;
    }
    __syncthreads();
    // emit uv records in sorted order: per-bin runs (coalesced)
    for (int s = t; s < cnum; s += 256) {
        int lid = slid[s];
        float2 q = suv[lid];
        int b = binof(q.x, q.y);
        unsigned pos = goff[b] + ((unsigned)s - lbase[b]);
        uv_s[pos] = q;
        if (idxp) idxp[pos] = (unsigned)(cb + lid);
    }
}

// ---- bilinear tap from row-pair half2 texture ----
__device__ __forceinline__ float sample_level(const __half2* __restrict__ R,
                                              const int S, const float gx,
                                              const float gy) {
    const float halfS = 0.5f * (float)S;
    float x = (gx + 1.0f) * halfS - 0.5f;
    float y = (gy + 1.0f) * halfS - 0.5f;
    float xf = floorf(x), yf = floorf(y);
    float wx = x - xf, wy = y - yf;
    int x0 = (int)xf, y0 = (int)yf;

    int yc = min(max(y0, 0), S - 1);
    float wa = (y0 >= 0) ? (1.0f - wy) : wy;
    if (y0 < -1 || y0 >= S) wa = 0.0f;
    float wb = (y0 >= 0 && y0 < S - 1) ? wy : 0.0f;

    int xb = min(max(x0, 0), S - 2);
    bool xin = (x0 >= 0) && (x0 <= S - 2);
    float wxa = xin ? (1.0f - wx) : ((x0 == -1) ? wx : 0.0f);
    float wxb = xin ? wx : ((x0 == S - 1) ? (1.0f - wx) : 0.0f);

    uint2 q;
    __builtin_memcpy(&q, (const char*)(R + (size_t)yc * (size_t)S + xb), 8);
    __half2 ca = *(const __half2*)&q.x;
    __half2 cb = *(const __half2*)&q.y;
    float2 fa = __half22float2(ca);
    float2 fb = __half22float2(cb);
    float cola = fmaf(wa, fa.x, wb * fa.y);
    float colb = fmaf(wa, fb.x, wb * fb.y);
    return fmaf(wxa, cola, wxb * colb);
}

__device__ __forceinline__ float sample_point(const __half2* __restrict__ r1,
                                              const __half2* __restrict__ r2,
                                              const __half2* __restrict__ r3,
                                              const __half2* __restrict__ r4,
                                              float ux, float uy) {
    float gx = ux * 2.0f - 1.0f;
    float gy = uy * 2.0f - 1.0f;
    float acc = sample_level(r1, 2048, gx, gy);
    acc += sample_level(r2, 1024, gx, gy);
    acc += sample_level(r3, 512, gx, gy);
    acc += sample_level(r4, 256, gx, gy);
    return acc;
}

// ---- kernel C: sample in sorted order -> val_s (fully coalesced, 4 pts/thr) ----
__global__ __launch_bounds__(256) void lappyr_sample4(
    const float2* __restrict__ uv_s, const __half2* __restrict__ r1,
    const __half2* __restrict__ r2, const __half2* __restrict__ r3,
    const __half2* __restrict__ r4, float* __restrict__ val_s, int n,
    int pinned) {
    int blk = blockIdx.x;
    int sb = pinned ? ((blk % NXCD) * (SEG / 1024) + blk / NXCD) : blk;
    int base = sb * 1024 + threadIdx.x * 4;
    if (base + 3 < n) {
        const f32x4* u4 = (const f32x4*)(uv_s + base);
        f32x4 a = __builtin_nontemporal_load(u4);
        f32x4 b = __builtin_nontemporal_load(u4 + 1);
        f32x4 res;
        res.x = sample_point(r1, r2, r3, r4, a.x, a.y);
        res.y = sample_point(r1, r2, r3, r4, a.z, a.w);
        res.z = sample_point(r1, r2, r3, r4, b.x, b.y);
        res.w = sample_point(r1, r2, r3, r4, b.z, b.w);
        *(f32x4*)(val_s + base) = res;  // cached: re-read by unsort on same XCD
    } else {
        for (int j = 0; j < 4; ++j) {
            int p = base + j;
            if (p < n) {
                float2 q = uv_s[p];
                val_s[p] = sample_point(r1, r2, r3, r4, q.x, q.y);
            }
        }
    }
}

// ---- kernel D: out[p] = val_s[inv[p]] (random READS, pinned L2 window) ----
__global__ __launch_bounds__(256) void lappyr_unsort4(
    const unsigned* __restrict__ inv, const float* __restrict__ val_s,
    float* __restrict__ out, int n, int pinned) {
    int blk = blockIdx.x;
    int sb = pinned ? ((blk % NXCD) * (SEG / 1024) + blk / NXCD) : blk;
    int base = sb * 1024 + threadIdx.x * 4;
    if (base + 3 < n) {
        u32x4 iv = __builtin_nontemporal_load((const u32x4*)(inv + base));
        f32x4 res;
        res.x = val_s[iv.x];
        res.y = val_s[iv.y];
        res.z = val_s[iv.z];
        res.w = val_s[iv.w];
        __builtin_nontemporal_store(res, (f32x4*)(out + base));
    } else {
        for (int j = 0; j < 4; ++j) {
            int p = base + j;
            if (p < n) out[p] = val_s[inv[p]];
        }
    }
}

// ---- middle fallback: round-4 fused sample+scatter (2 pts/thread) ----
__global__ __launch_bounds__(256) void lappyr_sample_sorted(
    const float2* __restrict__ uv_s, const unsigned* __restrict__ idx_s,
    const __half2* __restrict__ r1, const __half2* __restrict__ r2,
    const __half2* __restrict__ r3, const __half2* __restrict__ r4,
    float* __restrict__ out, int n, int pinned) {
    int blk = blockIdx.x;
    int sb = pinned ? ((blk % NXCD) * (SEG / 512) + blk / NXCD) : blk;
    int i = sb * 256 + threadIdx.x;
    int p0 = i * 2;
    if (p0 >= n) return;
    if (p0 + 1 < n) {
        f32x4 q = __builtin_nontemporal_load((const f32x4*)uv_s + i);
        u32x2 id = __builtin_nontemporal_load((const u32x2*)idx_s + i);
        float a0 = sample_point(r1, r2, r3, r4, q.x, q.y);
        float a1 = sample_point(r1, r2, r3, r4, q.z, q.w);
        out[id.x] = a0;
        out[id.y] = a1;
    } else {
        float2 q = uv_s[p0];
        out[idx_s[p0]] = sample_point(r1, r2, r3, r4, q.x, q.y);
    }
}

// ---- fallback A: unsorted sampling over repacked levels ----
__global__ __launch_bounds__(256) void lappyr_sample_kernel(
    const float2* __restrict__ uv, const __half2* __restrict__ r1,
    const __half2* __restrict__ r2, const __half2* __restrict__ r3,
    const __half2* __restrict__ r4, float* __restrict__ out, int n) {
    int i = blockIdx.x * blockDim.x + threadIdx.x;
    if (i >= n) return;
    float2 p = uv[i];
    out[i] = sample_point(r1, r2, r3, r4, p.x, p.y);
}

// ---- fallback B (ws too small): direct f32 sampling ----
__device__ __forceinline__ float bilin_f32(const float* __restrict__ img,
                                           const int S, const float gx,
                                           const float gy) {
    const float halfS = 0.5f * (float)S;
    float x = (gx + 1.0f) * halfS - 0.5f;
    float y = (gy + 1.0f) * halfS - 0.5f;
    float xf = floorf(x), yf = floorf(y);
    float wx = x - xf, wy = y - yf;
    int x0 = (int)xf, y0 = (int)yf, x1 = x0 + 1, y1 = y0 + 1;
    float ex0 = (x0 >= 0 && x0 < S) ? (1.0f - wx) : 0.0f;
    float ex1 = (x1 >= 0 && x1 < S) ? wx : 0.0f;
    float ey0 = (y0 >= 0 && y0 < S) ? (1.0f - wy) : 0.0f;
    float ey1 = (y1 >= 0 && y1 < S) ? wy : 0.0f;
    int xc0 = min(max(x0, 0), S - 1), xc1 = min(max(x1, 0), S - 1);
    int yc0 = min(max(y0, 0), S - 1), yc1 = min(max(y1, 0), S - 1);
    const float* r0 = img + (size_t)yc0 * S;
    const float* r1 = img + (size_t)yc1 * S;
    return ey0 * fmaf(ex0, r0[xc0], ex1 * r0[xc1]) +
           ey1 * fmaf(ex0, r1[xc0], ex1 * r1[xc1]);
}

__global__ __launch_bounds__(256) void lappyr_f32_kernel(
    const float2* __restrict__ uv, const float* __restrict__ l1,
    const float* __restrict__ l2, const float* __restrict__ l3,
    const float* __restrict__ l4, float* __restrict__ out, int n) {
    int i = blockIdx.x * blockDim.x + threadIdx.x;
    if (i >= n) return;
    float2 p = uv[i];
    float gx = p.x * 2.0f - 1.0f;
    float gy = p.y * 2.0f - 1.0f;
    float acc = bilin_f32(l1, 2048, gx, gy);
    acc += bilin_f32(l2, 1024, gx, gy);
    acc += bilin_f32(l3, 512, gx, gy);
    acc += bilin_f32(l4, 256, gx, gy);
    out[i] = acc;
}

extern "C" void kernel_launch(void* const* d_in, const int* in_sizes, int n_in,
                              void* d_out, int out_size, void* d_ws, size_t ws_size,
                              hipStream_t stream) {
    const float2* uv = (const float2*)d_in[0];
    const float* l1 = (const float*)d_in[1];
    const float* l2 = (const float*)d_in[2];
    const float* l3 = (const float*)d_in[3];
    const float* l4 = (const float*)d_in[4];
    float* out = (float*)d_out;
    int n = out_size;

    const size_t n1 = 2048u * 2048u, n2 = 1024u * 1024u, n3 = 512u * 512u,
                 n4 = 256u * 256u;
    const size_t ntot = n1 + n2 + n3 + n4;
    const size_t rep_bytes = ntot * sizeof(__half2);  // ~21.25 MiB

    int nseg = (n + SEG - 1) / SEG;
    size_t tbl_bytes = (size_t)nseg * K * 4 * 2;  // hist + cursor

    // new layout (gather-unsort): rep | uv_s | inv | val | hist | cursor
    size_t off_uvs = (rep_bytes + 255) & ~(size_t)255;
    size_t off_inv = off_uvs + (size_t)n * 8;
    size_t off_val = off_inv + (size_t)n * 4;
    size_t off_hist2 = (off_val + (size_t)n * 4 + 255) & ~(size_t)255;
    size_t need2 = off_hist2 + tbl_bytes;
    // old layout (scatter): rep | uv_s | idx | hist | cursor
    size_t off_idx = off_uvs + (size_t)n * 8;
    size_t off_hist1 = (off_idx + (size_t)n * 4 + 255) & ~(size_t)255;
    size_t need1 = off_hist1 + tbl_bytes;

    int repack_blocks = (int)((ntot + 255) / 256);

    if (ws_size >= rep_bytes) {
        char* ws = (char*)d_ws;
        __half2* r1 = (__half2*)ws;
        __half2* r2 = r1 + n1;
        __half2* r3 = r2 + n2;
        __half2* r4 = r3 + n3;
        int pinned = (n == NXCD * SEG) ? 1 : 0;
        int hist_blocks = (n + HB - 1) / HB;
        int ga = max(repack_blocks, hist_blocks);
        int nchunks = (n + CHUNK - 1) / CHUNK;
        if (ws_size >= need2 && n > 0) {
            float2* uv_s = (float2*)(ws + off_uvs);
            unsigned* inv = (unsigned*)(ws + off_inv);
            float* val_s = (float*)(ws + off_val);
            unsigned* hist = (unsigned*)(ws + off_hist2);
            unsigned* cursor = hist + (size_t)nseg * K;
            hipMemsetAsync(ws + off_hist2, 0, tbl_bytes, stream);
            repack_hist_kernel<<<ga, 256, 0, stream>>>(l1, l2, l3, l4, r1, r2, r3,
                                                       r4, uv, hist, n);
            partition_kernel<<<nchunks, 256, 0, stream>>>(
                uv, hist, cursor, uv_s, inv, nullptr, n, pinned);
            int nb4 = (n + 1023) / 1024;
            lappyr_sample4<<<nb4, 256, 0, stream>>>(uv_s, r1, r2, r3, r4, val_s,
                                                    n, pinned);
            lappyr_unsort4<<<nb4, 256, 0, stream>>>(inv, val_s, out, n, pinned);
        } else if (ws_size >= need1 && n > 0) {
            float2* uv_s = (float2*)(ws + off_uvs);
            unsigned* idx_s = (unsigned*)(ws + off_idx);
            unsigned* hist = (unsigned*)(ws + off_hist1);
            unsigned* cursor = hist + (size_t)nseg * K;
            hipMemsetAsync(ws + off_hist1, 0, tbl_bytes, stream);
            repack_hist_kernel<<<ga, 256, 0, stream>>>(l1, l2, l3, l4, r1, r2, r3,
                                                       r4, uv, hist, n);
            partition_kernel<<<nchunks, 256, 0, stream>>>(
                uv, hist, cursor, uv_s, nullptr, idx_s, n, pinned);
            int nh = (n + 1) / 2;
            lappyr_sample_sorted<<<(nh + 255) / 256, 256, 0, stream>>>(
                uv_s, idx_s, r1, r2, r3, r4, out, n, pinned);
        } else {
            repack_hist_kernel<<<repack_blocks, 256, 0, stream>>>(
                l1, l2, l3, l4, r1, r2, r3, r4, uv, nullptr, n);
            lappyr_sample_kernel<<<(n + 255) / 256, 256, 0, stream>>>(
                uv, r1, r2, r3, r4, out, n);
        }
    } else {
        lappyr_f32_kernel<<<(n + 255) / 256, 256, 0, stream>>>(uv, l1, l2, l3, l4,
                                                               out, n);
    }
}

// Round 6
// 312.323 us; speedup vs baseline: 2.1051x; 1.0004x over previous
//
#include <hip/hip_runtime.h>
#include <hip/hip_fp16.h>

// Layout: per level, fp16 ROW-PAIR repack R[y][x] = half2(img[y][x], img[min(y+1,S-1)][x]).
// One bilinear quad = one 8-byte load, zero-padding folded into weights.
//
// Round 6: partition_kernel was the new top dispatch (98us) -- latency-bound at
// 18% occupancy (54KB LDS, 2 blocks/CU), NOT bandwidth (1.7TB/s). Slimmed:
//  - scan_kernel pre-initializes cursor[seg][bin] = segstart + scan(hist), so
//    partition's atomicAdd returns the global base directly (kills the per-block
//    1024-bin segment scan, ~16 syncs)
//  - no staged input copy: count+rank re-read uv coalesced (L2-hot 2nd pass);
//    rank writes points straight into bin-sorted LDS slots; emit = coalesced copy
//  - LDS 54->46KB (3 blocks/CU), LDS ops/pt 6->2, inv written as u32x2
// Old partition kept as partition_idx_kernel for the ws-size fallback path.

typedef unsigned int u32x2 __attribute__((ext_vector_type(2)));
typedef unsigned int u32x4 __attribute__((ext_vector_type(4)));
typedef float f32x4 __attribute__((ext_vector_type(4)));

#define K 1024                 // 32x32 uv bins
#define CHUNK 4096             // points per partition block
#define HB 4096                // points per hist block (in repack kernel)
#define SEG (CHUNK * 256)      // 1048576 pts/segment
#define NXCD 8

__device__ __forceinline__ int binof(float u, float v) {
    int bx = min(max((int)(u * 32.0f), 0), 31);
    int by = min(max((int)(v * 32.0f), 0), 31);
    return by * 32 + bx;
}

// ---- kernel A: repack all 4 levels + per-segment 1024-bin histogram ----
__global__ __launch_bounds__(256) void repack_hist_kernel(
    const float* __restrict__ l1, const float* __restrict__ l2,
    const float* __restrict__ l3, const float* __restrict__ l4,
    __half2* __restrict__ r1, __half2* __restrict__ r2,
    __half2* __restrict__ r3, __half2* __restrict__ r4,
    const float2* __restrict__ uv, unsigned* __restrict__ hist, int n) {
    const int n1 = 2048 * 2048, n2 = 1024 * 1024, n3 = 512 * 512, n4 = 256 * 256;
    int i = blockIdx.x * 256 + threadIdx.x;
    {
        const float* __restrict__ src = nullptr;
        __half2* __restrict__ dst = nullptr;
        int S = 0, logS = 0, j = 0;
        if (i < n1) {
            src = l1; dst = r1; S = 2048; logS = 11; j = i;
        } else if (i < n1 + n2) {
            src = l2; dst = r2; S = 1024; logS = 10; j = i - n1;
        } else if (i < n1 + n2 + n3) {
            src = l3; dst = r3; S = 512; logS = 9; j = i - (n1 + n2);
        } else if (i < n1 + n2 + n3 + n4) {
            src = l4; dst = r4; S = 256; logS = 8; j = i - (n1 + n2 + n3);
        }
        if (src) {
            int y = j >> logS;
            float a = src[j];
            float b = src[(y < S - 1) ? (j + S) : j];
            dst[j] = __halves2half2(__float2half(a), __float2half(b));
        }
    }
    if (hist == nullptr) return;
    int base = blockIdx.x * HB;
    if (base >= n) return;
    __shared__ unsigned cnt[K];
    for (int b = threadIdx.x; b < K; b += 256) cnt[b] = 0u;
    __syncthreads();
    int m = min(HB, n - base);
    const f32x4* uv4 = (const f32x4*)(uv + base);
    int npair = m >> 1;
    for (int k2 = threadIdx.x; k2 < npair; k2 += 256) {
        f32x4 q = __builtin_nontemporal_load(&uv4[k2]);
        atomicAdd(&cnt[binof(q.x, q.y)], 1u);
        atomicAdd(&cnt[binof(q.z, q.w)], 1u);
    }
    if ((m & 1) && threadIdx.x == 0) {
        float2 q = uv[base + m - 1];
        atomicAdd(&cnt[binof(q.x, q.y)], 1u);
    }
    __syncthreads();
    int seg = base / SEG;
    unsigned* gh = hist + (size_t)seg * K;
    for (int b = threadIdx.x; b < K; b += 256) {
        unsigned v = cnt[b];
        if (v) atomicAdd(&gh[b], v);
    }
}

// ---- kernel A2: cursor[seg][b] = seg*SEG + exclusive_scan(hist[seg]) ----
__global__ __launch_bounds__(256) void scan_kernel(
    const unsigned* __restrict__ hist, unsigned* __restrict__ cursor) {
    int seg = blockIdx.x;
    const unsigned* h = hist + (size_t)seg * K;
    unsigned* c = cursor + (size_t)seg * K;
    __shared__ unsigned part[256];
    int t = threadIdx.x;
    unsigned v0 = h[t * 4], v1 = h[t * 4 + 1], v2 = h[t * 4 + 2], v3 = h[t * 4 + 3];
    unsigned s1 = v0, s2 = v0 + v1, s3 = v0 + v1 + v2;
    part[t] = s3 + v3;
    __syncthreads();
    for (int off = 1; off < 256; off <<= 1) {
        unsigned x = (t >= off) ? part[t - off] : 0u;
        __syncthreads();
        part[t] += x;
        __syncthreads();
    }
    unsigned tb = (t > 0) ? part[t - 1] : 0u;
    unsigned segstart = (unsigned)((size_t)seg * SEG);
    c[t * 4] = segstart + tb;
    c[t * 4 + 1] = segstart + tb + s1;
    c[t * 4 + 2] = segstart + tb + s2;
    c[t * 4 + 3] = segstart + tb + s3;
}

// ---- kernel B (slim): partition -> bin-sorted uv records + inverse perm ----
__global__ __launch_bounds__(256) void partition_kernel(
    const float2* __restrict__ uv, unsigned* __restrict__ cursor,
    float2* __restrict__ uv_s, unsigned* __restrict__ invp, int n, int pinned) {
    __shared__ float2 ssort[CHUNK];   // 32 KB: bin-sorted staging
    __shared__ unsigned cnt[K];       // 4 KB
    __shared__ unsigned lbase[K];     // 4 KB
    __shared__ unsigned gdiff[K];     // 4 KB: global_pos = gdiff[b] + local_slot
    __shared__ unsigned part[256];    // 1 KB
    int t = threadIdx.x;
    int blk = blockIdx.x;
    int c = pinned ? ((blk % NXCD) * (SEG / CHUNK) + blk / NXCD) : blk;
    int cb = c * CHUNK;
    if (cb >= n) return;
    int cnum = min(CHUNK, n - cb);
    int seg = cb / SEG;  // CHUNK divides SEG -> no straddle

    for (int b = t; b < K; b += 256) cnt[b] = 0u;
    __syncthreads();
    // pass 1: count (coalesced global read; HBM/L3)
    const f32x4* uv4 = (const f32x4*)(uv + cb);
    int npair = cnum >> 1;
    for (int k2 = t; k2 < npair; k2 += 256) {
        f32x4 q = uv4[k2];
        atomicAdd(&cnt[binof(q.x, q.y)], 1u);
        atomicAdd(&cnt[binof(q.z, q.w)], 1u);
    }
    if ((cnum & 1) && t == 0) {
        float2 q = uv[cb + cnum - 1];
        atomicAdd(&cnt[binof(q.x, q.y)], 1u);
    }
    __syncthreads();
    // local exclusive scan -> lbase; reserve global ranges (cursor holds bases)
    {
        unsigned v0 = cnt[t * 4], v1 = cnt[t * 4 + 1], v2 = cnt[t * 4 + 2],
                 v3 = cnt[t * 4 + 3];
        unsigned s1 = v0, s2 = v0 + v1, s3 = v0 + v1 + v2;
        part[t] = s3 + v3;
        __syncthreads();
        for (int off = 1; off < 256; off <<= 1) {
            unsigned x = (t >= off) ? part[t - off] : 0u;
            __syncthreads();
            part[t] += x;
            __syncthreads();
        }
        unsigned tb = (t > 0) ? part[t - 1] : 0u;
        unsigned lb[4] = {tb, tb + s1, tb + s2, tb + s3};
        unsigned cv[4] = {v0, v1, v2, v3};
        for (int j = 0; j < 4; ++j) {
            int b = t * 4 + j;
            lbase[b] = lb[j];
            unsigned goff =
                cv[j] ? atomicAdd(&cursor[(size_t)seg * K + b], cv[j]) : 0u;
            gdiff[b] = goff - lb[j];
        }
    }
    __syncthreads();
    for (int b = t; b < K; b += 256) cnt[b] = 0u;
    __syncthreads();
    // pass 2: rank (coalesced re-read, L2-hot); stage sorted; write inv (u32x2)
    for (int k2 = t; k2 < npair; k2 += 256) {
        f32x4 q = uv4[k2];
        int ba = binof(q.x, q.y);
        unsigned sa = lbase[ba] + atomicAdd(&cnt[ba], 1u);
        ssort[sa] = make_float2(q.x, q.y);
        int bb = binof(q.z, q.w);
        unsigned sb = lbase[bb] + atomicAdd(&cnt[bb], 1u);
        ssort[sb] = make_float2(q.z, q.w);
        if (invp) {
            u32x2 iv;
            iv.x = gdiff[ba] + sa;
            iv.y = gdiff[bb] + sb;
            *(u32x2*)(invp + cb + k2 * 2) = iv;
        }
    }
    if ((cnum & 1) && t == 0) {
        float2 q = uv[cb + cnum - 1];
        int b = binof(q.x, q.y);
        unsigned s = lbase[b] + atomicAdd(&cnt[b], 1u);
        ssort[s] = q;
        if (invp) invp[cb + cnum - 1] = gdiff[b] + s;
    }
    __syncthreads();
    // pass 3: emit coalesced (per-bin runs)
    for (int s = t; s < cnum; s += 256) {
        float2 q = ssort[s];
        int b = binof(q.x, q.y);
        uv_s[gdiff[b] + (unsigned)s] = q;
    }
}

// ---- kernel B-old (fallback middle path): partition with idx_s output ----
__global__ __launch_bounds__(256) void partition_idx_kernel(
    const float2* __restrict__ uv, const unsigned* __restrict__ hist,
    unsigned* __restrict__ cursor, float2* __restrict__ uv_s,
    unsigned* __restrict__ idxp, int n, int pinned) {
    __shared__ float2 suv[CHUNK];
    __shared__ unsigned short slid[CHUNK];
    __shared__ unsigned cnt[K];
    __shared__ unsigned lbase[K];
    __shared__ unsigned goff[K];
    __shared__ unsigned part[256];
    int t = threadIdx.x;
    int blk = blockIdx.x;
    int c = pinned ? ((blk % NXCD) * (SEG / CHUNK) + blk / NXCD) : blk;
    int cb = c * CHUNK;
    if (cb >= n) return;
    int cnum = min(CHUNK, n - cb);
    int seg = cb / SEG;
    unsigned segstart = (unsigned)((size_t)seg * SEG);
    {
        const f32x4* uv4 = (const f32x4*)(uv + cb);
        int npair = cnum >> 1;
        for (int k2 = t; k2 < npair; k2 += 256) {
            f32x4 q = uv4[k2];
            suv[k2 * 2] = make_float2(q.x, q.y);
            suv[k2 * 2 + 1] = make_float2(q.z, q.w);
        }
        if ((cnum & 1) && t == 0) suv[cnum - 1] = uv[cb + cnum - 1];
    }
    for (int b = t; b < K; b += 256) cnt[b] = 0u;
    __syncthreads();
    for (int k = t; k < cnum; k += 256)
        atomicAdd(&cnt[binof(suv[k].x, suv[k].y)], 1u);
    __syncthreads();
    {
        unsigned v0 = cnt[t * 4], v1 = cnt[t * 4 + 1], v2 = cnt[t * 4 + 2],
                 v3 = cnt[t * 4 + 3];
        unsigned s1 = v0, s2 = v0 + v1, s3 = v0 + v1 + v2;
        part[t] = s3 + v3;
        __syncthreads();
        for (int off = 1; off < 256; off <<= 1) {
            unsigned x = (t >= off) ? part[t - off] : 0u;
            __syncthreads();
            part[t] += x;
            __syncthreads();
        }
        unsigned tb = (t > 0) ? part[t - 1] : 0u;
        lbase[t * 4] = tb;
        lbase[t * 4 + 1] = tb + s1;
        lbase[t * 4 + 2] = tb + s2;
        lbase[t * 4 + 3] = tb + s3;
    }
    __syncthreads();
    {
        const unsigned* h = hist + (size_t)seg * K;
        unsigned v0 = h[t * 4], v1 = h[t * 4 + 1], v2 = h[t * 4 + 2],
                 v3 = h[t * 4 + 3];
        unsigned s1 = v0, s2 = v0 + v1, s3 = v0 + v1 + v2;
        part[t] = s3 + v3;
        __syncthreads();
        for (int off = 1; off < 256; off <<= 1) {
            unsigned x = (t >= off) ? part[t - off] : 0u;
            __syncthreads();
            part[t] += x;
            __syncthreads();
        }
        unsigned tb = (t > 0) ? part[t - 1] : 0u;
        unsigned sbv[4] = {tb, tb + s1, tb + s2, tb + s3};
        for (int j = 0; j < 4; ++j) {
            int b = t * 4 + j;
            unsigned cc = cnt[b];
            unsigned r = cc ? atomicAdd(&cursor[(size_t)seg * K + b], cc) : 0u;
            goff[b] = segstart + sbv[j] + r;
        }
    }
    __syncthreads();
    for (int b = t; b < K; b += 256) cnt[b] = 0u;
    __syncthreads();
    for (int k = t; k < cnum; k += 256) {
        int b = binof(suv[k].x, suv[k].y);
        unsigned r = atomicAdd(&cnt[b], 1u);
        slid[lbase[b] + r] = (unsigned short)k;
    }
    __syncthreads();
    for (int s = t; s < cnum; s += 256) {
        int lid = slid[s];
        float2 q = suv[lid];
        int b = binof(q.x, q.y);
        unsigned pos = goff[b] + ((unsigned)s - lbase[b]);
        uv_s[pos] = q;
        idxp[pos] = (unsigned)(cb + lid);
    }
}

// ---- bilinear tap from row-pair half2 texture ----
__device__ __forceinline__ float sample_level(const __half2* __restrict__ R,
                                              const int S, const float gx,
                                              const float gy) {
    const float halfS = 0.5f * (float)S;
    float x = (gx + 1.0f) * halfS - 0.5f;
    float y = (gy + 1.0f) * halfS - 0.5f;
    float xf = floorf(x), yf = floorf(y);
    float wx = x - xf, wy = y - yf;
    int x0 = (int)xf, y0 = (int)yf;

    int yc = min(max(y0, 0), S - 1);
    float wa = (y0 >= 0) ? (1.0f - wy) : wy;
    if (y0 < -1 || y0 >= S) wa = 0.0f;
    float wb = (y0 >= 0 && y0 < S - 1) ? wy : 0.0f;

    int xb = min(max(x0, 0), S - 2);
    bool xin = (x0 >= 0) && (x0 <= S - 2);
    float wxa = xin ? (1.0f - wx) : ((x0 == -1) ? wx : 0.0f);
    float wxb = xin ? wx : ((x0 == S - 1) ? (1.0f - wx) : 0.0f);

    uint2 q;
    __builtin_memcpy(&q, (const char*)(R + (size_t)yc * (size_t)S + xb), 8);
    __half2 ca = *(const __half2*)&q.x;
    __half2 cb = *(const __half2*)&q.y;
    float2 fa = __half22float2(ca);
    float2 fb = __half22float2(cb);
    float cola = fmaf(wa, fa.x, wb * fa.y);
    float colb = fmaf(wa, fb.x, wb * fb.y);
    return fmaf(wxa, cola, wxb * colb);
}

__device__ __forceinline__ float sample_point(const __half2* __restrict__ r1,
                                              const __half2* __restrict__ r2,
                                              const __half2* __restrict__ r3,
                                              const __half2* __restrict__ r4,
                                              float ux, float uy) {
    float gx = ux * 2.0f - 1.0f;
    float gy = uy * 2.0f - 1.0f;
    float acc = sample_level(r1, 2048, gx, gy);
    acc += sample_level(r2, 1024, gx, gy);
    acc += sample_level(r3, 512, gx, gy);
    acc += sample_level(r4, 256, gx, gy);
    return acc;
}

// ---- kernel C: sample in sorted order -> val_s (fully coalesced) ----
__global__ __launch_bounds__(256) void lappyr_sample4(
    const float2* __restrict__ uv_s, const __half2* __restrict__ r1,
    const __half2* __restrict__ r2, const __half2* __restrict__ r3,
    const __half2* __restrict__ r4, float* __restrict__ val_s, int n,
    int pinned) {
    int blk = blockIdx.x;
    int sb = pinned ? ((blk % NXCD) * (SEG / 1024) + blk / NXCD) : blk;
    int base = sb * 1024 + threadIdx.x * 4;
    if (base + 3 < n) {
        const f32x4* u4 = (const f32x4*)(uv_s + base);
        f32x4 a = __builtin_nontemporal_load(u4);
        f32x4 b = __builtin_nontemporal_load(u4 + 1);
        f32x4 res;
        res.x = sample_point(r1, r2, r3, r4, a.x, a.y);
        res.y = sample_point(r1, r2, r3, r4, a.z, a.w);
        res.z = sample_point(r1, r2, r3, r4, b.x, b.y);
        res.w = sample_point(r1, r2, r3, r4, b.z, b.w);
        *(f32x4*)(val_s + base) = res;
    } else {
        for (int j = 0; j < 4; ++j) {
            int p = base + j;
            if (p < n) {
                float2 q = uv_s[p];
                val_s[p] = sample_point(r1, r2, r3, r4, q.x, q.y);
            }
        }
    }
}

// ---- kernel D: out[p] = val_s[inv[p]] (random READS, pinned L2 window) ----
__global__ __launch_bounds__(256) void lappyr_unsort4(
    const unsigned* __restrict__ inv, const float* __restrict__ val_s,
    float* __restrict__ out, int n, int pinned) {
    int blk = blockIdx.x;
    int sb = pinned ? ((blk % NXCD) * (SEG / 1024) + blk / NXCD) : blk;
    int base = sb * 1024 + threadIdx.x * 4;
    if (base + 3 < n) {
        u32x4 iv = __builtin_nontemporal_load((const u32x4*)(inv + base));
        f32x4 res;
        res.x = val_s[iv.x];
        res.y = val_s[iv.y];
        res.z = val_s[iv.z];
        res.w = val_s[iv.w];
        __builtin_nontemporal_store(res, (f32x4*)(out + base));
    } else {
        for (int j = 0; j < 4; ++j) {
            int p = base + j;
            if (p < n) out[p] = val_s[inv[p]];
        }
    }
}

// ---- middle fallback: fused sample+scatter (2 pts/thread) ----
__global__ __launch_bounds__(256) void lappyr_sample_sorted(
    const float2* __restrict__ uv_s, const unsigned* __restrict__ idx_s,
    const __half2* __restrict__ r1, const __half2* __restrict__ r2,
    const __half2* __restrict__ r3, const __half2* __restrict__ r4,
    float* __restrict__ out, int n, int pinned) {
    int blk = blockIdx.x;
    int sb = pinned ? ((blk % NXCD) * (SEG / 512) + blk / NXCD) : blk;
    int i = sb * 256 + threadIdx.x;
    int p0 = i * 2;
    if (p0 >= n) return;
    if (p0 + 1 < n) {
        f32x4 q = __builtin_nontemporal_load((const f32x4*)uv_s + i);
        u32x2 id = __builtin_nontemporal_load((const u32x2*)idx_s + i);
        float a0 = sample_point(r1, r2, r3, r4, q.x, q.y);
        float a1 = sample_point(r1, r2, r3, r4, q.z, q.w);
        out[id.x] = a0;
        out[id.y] = a1;
    } else {
        float2 q = uv_s[p0];
        out[idx_s[p0]] = sample_point(r1, r2, r3, r4, q.x, q.y);
    }
}

// ---- fallback A: unsorted sampling over repacked levels ----
__global__ __launch_bounds__(256) void lappyr_sample_kernel(
    const float2* __restrict__ uv, const __half2* __restrict__ r1,
    const __half2* __restrict__ r2, const __half2* __restrict__ r3,
    const __half2* __restrict__ r4, float* __restrict__ out, int n) {
    int i = blockIdx.x * blockDim.x + threadIdx.x;
    if (i >= n) return;
    float2 p = uv[i];
    out[i] = sample_point(r1, r2, r3, r4, p.x, p.y);
}

// ---- fallback B (ws too small): direct f32 sampling ----
__device__ __forceinline__ float bilin_f32(const float* __restrict__ img,
                                           const int S, const float gx,
                                           const float gy) {
    const float halfS = 0.5f * (float)S;
    float x = (gx + 1.0f) * halfS - 0.5f;
    float y = (gy + 1.0f) * halfS - 0.5f;
    float xf = floorf(x), yf = floorf(y);
    float wx = x - xf, wy = y - yf;
    int x0 = (int)xf, y0 = (int)yf, x1 = x0 + 1, y1 = y0 + 1;
    float ex0 = (x0 >= 0 && x0 < S) ? (1.0f - wx) : 0.0f;
    float ex1 = (x1 >= 0 && x1 < S) ? wx : 0.0f;
    float ey0 = (y0 >= 0 && y0 < S) ? (1.0f - wy) : 0.0f;
    float ey1 = (y1 >= 0 && y1 < S) ? wy : 0.0f;
    int xc0 = min(max(x0, 0), S - 1), xc1 = min(max(x1, 0), S - 1);
    int yc0 = min(max(y0, 0), S - 1), yc1 = min(max(y1, 0), S - 1);
    const float* r0 = img + (size_t)yc0 * S;
    const float* r1 = img + (size_t)yc1 * S;
    return ey0 * fmaf(ex0, r0[xc0], ex1 * r0[xc1]) +
           ey1 * fmaf(ex0, r1[xc0], ex1 * r1[xc1]);
}

__global__ __launch_bounds__(256) void lappyr_f32_kernel(
    const float2* __restrict__ uv, const float* __restrict__ l1,
    const float* __restrict__ l2, const float* __restrict__ l3,
    const float* __restrict__ l4, float* __restrict__ out, int n) {
    int i = blockIdx.x * blockDim.x + threadIdx.x;
    if (i >= n) return;
    float2 p = uv[i];
    float gx = p.x * 2.0f - 1.0f;
    float gy = p.y * 2.0f - 1.0f;
    float acc = bilin_f32(l1, 2048, gx, gy);
    acc += bilin_f32(l2, 1024, gx, gy);
    acc += bilin_f32(l3, 512, gx, gy);
    acc += bilin_f32(l4, 256, gx, gy);
    out[i] = acc;
}

extern "C" void kernel_launch(void* const* d_in, const int* in_sizes, int n_in,
                              void* d_out, int out_size, void* d_ws, size_t ws_size,
                              hipStream_t stream) {
    const float2* uv = (const float2*)d_in[0];
    const float* l1 = (const float*)d_in[1];
    const float* l2 = (const float*)d_in[2];
    const float* l3 = (const float*)d_in[3];
    const float* l4 = (const float*)d_in[4];
    float* out = (float*)d_out;
    int n = out_size;

    const size_t n1 = 2048u * 2048u, n2 = 1024u * 1024u, n3 = 512u * 512u,
                 n4 = 256u * 256u;
    const size_t ntot = n1 + n2 + n3 + n4;
    const size_t rep_bytes = ntot * sizeof(__half2);  // ~21.25 MiB

    int nseg = (n + SEG - 1) / SEG;
    size_t tbl_bytes = (size_t)nseg * K * 4 * 2;  // hist + cursor

    // gather-unsort layout: rep | uv_s | inv | val | hist | cursor
    size_t off_uvs = (rep_bytes + 255) & ~(size_t)255;
    size_t off_inv = off_uvs + (size_t)n * 8;
    size_t off_val = off_inv + (size_t)n * 4;
    size_t off_hist2 = (off_val + (size_t)n * 4 + 255) & ~(size_t)255;
    size_t need2 = off_hist2 + tbl_bytes;
    // scatter layout: rep | uv_s | idx | hist | cursor
    size_t off_idx = off_uvs + (size_t)n * 8;
    size_t off_hist1 = (off_idx + (size_t)n * 4 + 255) & ~(size_t)255;
    size_t need1 = off_hist1 + tbl_bytes;

    int repack_blocks = (int)((ntot + 255) / 256);

    if (ws_size >= rep_bytes) {
        char* ws = (char*)d_ws;
        __half2* r1 = (__half2*)ws;
        __half2* r2 = r1 + n1;
        __half2* r3 = r2 + n2;
        __half2* r4 = r3 + n3;
        int pinned = (n == NXCD * SEG) ? 1 : 0;
        int hist_blocks = (n + HB - 1) / HB;
        int ga = max(repack_blocks, hist_blocks);
        int nchunks = (n + CHUNK - 1) / CHUNK;
        if (ws_size >= need2 && n > 0) {
            float2* uv_s = (float2*)(ws + off_uvs);
            unsigned* inv = (unsigned*)(ws + off_inv);
            float* val_s = (float*)(ws + off_val);
            unsigned* hist = (unsigned*)(ws + off_hist2);
            unsigned* cursor = hist + (size_t)nseg * K;
            hipMemsetAsync(hist, 0, (size_t)nseg * K * 4, stream);  // hist only
            repack_hist_kernel<<<ga, 256, 0, stream>>>(l1, l2, l3, l4, r1, r2, r3,
                                                       r4, uv, hist, n);
            scan_kernel<<<nseg, 256, 0, stream>>>(hist, cursor);
            partition_kernel<<<nchunks, 256, 0, stream>>>(uv, cursor, uv_s, inv,
                                                          n, pinned);
            int nb4 = (n + 1023) / 1024;
            lappyr_sample4<<<nb4, 256, 0, stream>>>(uv_s, r1, r2, r3, r4, val_s,
                                                    n, pinned);
            lappyr_unsort4<<<nb4, 256, 0, stream>>>(inv, val_s, out, n, pinned);
        } else if (ws_size >= need1 && n > 0) {
            float2* uv_s = (float2*)(ws + off_uvs);
            unsigned* idx_s = (unsigned*)(ws + off_idx);
            unsigned* hist = (unsigned*)(ws + off_hist1);
            unsigned* cursor = hist + (size_t)nseg * K;
            hipMemsetAsync(hist, 0, tbl_bytes, stream);  // hist + cursor
            repack_hist_kernel<<<ga, 256, 0, stream>>>(l1, l2, l3, l4, r1, r2, r3,
                                                       r4, uv, hist, n);
            partition_idx_kernel<<<nchunks, 256, 0, stream>>>(
                uv, hist, cursor, uv_s, idx_s, n, pinned);
            int nh = (n + 1) / 2;
            lappyr_sample_sorted<<<(nh + 255) / 256, 256, 0, stream>>>(
                uv_s, idx_s, r1, r2, r3, r4, out, n, pinned);
        } else {
            repack_hist_kernel<<<repack_blocks, 256, 0, stream>>>(
                l1, l2, l3, l4, r1, r2, r3, r4, uv, nullptr, n);
            lappyr_sample_kernel<<<(n + 255) / 256, 256, 0, stream>>>(
                uv, r1, r2, r3, r4, out, n);
        }
    } else {
        lappyr_f32_kernel<<<(n + 255) / 256, 256, 0, stream>>>(uv, l1, l2, l3, l4,
                                                               out, n);
    }
}

// Round 8
// 302.552 us; speedup vs baseline: 2.1731x; 1.0323x over previous
//
#include <hip/hip_runtime.h>
#include <hip/hip_fp16.h>

// Layout: per level, fp16 ROW-PAIR repack R[y][x] = half2(img[y][x], img[min(y+1,S-1)][x]).
// One bilinear quad = one 8-byte load, zero-padding folded into weights.
//
// Round 8 (= round 7 fixed: ext_vector element address -> scalar temps):
//  - repack_hist persists per-chunk histograms chist[chunk][bin]; cursor_kernel
//    builds a DETERMINISTIC per-(seg,bin,chunk) global-base table via wave
//    __shfl_up scans. Partition loses its count pass AND all contended cursor
//    atomics -- it just loads chist + cursor.
//  - chist/cursor/seghist (~16 MB) aliased into the val_s slab (dead until
//    sample4) -> no workspace growth.
//  - repack vectorized x4 (f32x4 row loads, 16B packed store).
// Sort/segment/XCD-pinning design unchanged (validated rounds 3-6).

typedef unsigned int u32x2 __attribute__((ext_vector_type(2)));
typedef unsigned int u32x4 __attribute__((ext_vector_type(4)));
typedef float f32x4 __attribute__((ext_vector_type(4)));

#define K 1024                 // 32x32 uv bins
#define CHUNK 4096             // points per partition block == hist block
#define HB 4096
#define SEG (CHUNK * 256)      // 1048576 pts/segment
#define NXCD 8

__device__ __forceinline__ int binof(float u, float v) {
    int bx = min(max((int)(u * 32.0f), 0), 31);
    int by = min(max((int)(v * 32.0f), 0), 31);
    return by * 32 + bx;
}

__device__ __forceinline__ unsigned pack2(float lo, float hi) {
    __half2 h = __halves2half2(__float2half(lo), __float2half(hi));
    unsigned w;
    __builtin_memcpy(&w, &h, 4);
    return w;
}

// ---- kernel A: repack all 4 levels (x4 vectorized) + per-chunk histogram ----
__global__ __launch_bounds__(256) void repack_hist_kernel(
    const float* __restrict__ l1, const float* __restrict__ l2,
    const float* __restrict__ l3, const float* __restrict__ l4,
    __half2* __restrict__ r1, __half2* __restrict__ r2,
    __half2* __restrict__ r3, __half2* __restrict__ r4,
    const float2* __restrict__ uv, unsigned* __restrict__ seghist,
    unsigned* __restrict__ chist, int n) {
    const int n1 = 2048 * 2048, n2 = 1024 * 1024, n3 = 512 * 512, n4 = 256 * 256;
    // --- repack share: 4 elements per thread (all level sizes % 4 == 0) ---
    {
        int e = (blockIdx.x * 256 + threadIdx.x) * 4;
        const float* __restrict__ src = nullptr;
        __half2* __restrict__ dst = nullptr;
        int S = 0, logS = 0, j = 0;
        if (e < n1) {
            src = l1; dst = r1; S = 2048; logS = 11; j = e;
        } else if (e < n1 + n2) {
            src = l2; dst = r2; S = 1024; logS = 10; j = e - n1;
        } else if (e < n1 + n2 + n3) {
            src = l3; dst = r3; S = 512; logS = 9; j = e - (n1 + n2);
        } else if (e < n1 + n2 + n3 + n4) {
            src = l4; dst = r4; S = 256; logS = 8; j = e - (n1 + n2 + n3);
        }
        if (src) {
            int y = j >> logS;  // j..j+3 same row (j%4==0, S%4==0)
            f32x4 a = *(const f32x4*)(src + j);
            f32x4 b = *(const f32x4*)(src + ((y < S - 1) ? (j + S) : j));
            u32x4 o = {pack2(a.x, b.x), pack2(a.y, b.y), pack2(a.z, b.z),
                       pack2(a.w, b.w)};
            *(u32x4*)(dst + j) = o;
        }
    }
    // --- histogram share: block c covers points [c*HB, (c+1)*HB) ---
    if (seghist == nullptr) return;
    int c = blockIdx.x;
    int base = c * HB;
    if (base >= n) return;
    __shared__ unsigned cnt[K];
    for (int b = threadIdx.x; b < K; b += 256) cnt[b] = 0u;
    __syncthreads();
    int m = min(HB, n - base);
    const f32x4* uv4 = (const f32x4*)(uv + base);
    int npair = m >> 1;
    for (int k2 = threadIdx.x; k2 < npair; k2 += 256) {
        f32x4 q = __builtin_nontemporal_load(&uv4[k2]);
        atomicAdd(&cnt[binof(q.x, q.y)], 1u);
        atomicAdd(&cnt[binof(q.z, q.w)], 1u);
    }
    if ((m & 1) && threadIdx.x == 0) {
        float2 q = uv[base + m - 1];
        atomicAdd(&cnt[binof(q.x, q.y)], 1u);
    }
    __syncthreads();
    int seg = base / SEG;
    unsigned* gh = seghist + (size_t)seg * K;
    for (int b = threadIdx.x; b < K; b += 256) {
        unsigned v = cnt[b];
        if (chist) chist[(size_t)c * K + b] = v;  // non-atomic, coalesced
        if (v) atomicAdd(&gh[b], v);
    }
}

// ---- kernel A2: deterministic cursor table ----
// cursor[(seg*K+b)*256 + c] = seg*SEG + excl_scan_bins(seghist[seg])[b]
//                           + excl_scan_chunks(chist[seg][*][b])[c]
__global__ __launch_bounds__(256) void cursor_kernel(
    const unsigned* __restrict__ seghist, const unsigned* __restrict__ chist,
    unsigned* __restrict__ cursor, int nchunks) {
    int seg = blockIdx.x >> 6;  // 64 blocks per segment
    int grp = blockIdx.x & 63;  // 16 bins per block
    const unsigned* h = seghist + (size_t)seg * K;
    __shared__ unsigned part[256];
    __shared__ unsigned base[K];
    int t = threadIdx.x;
    // block-wide exclusive scan of this segment's 1024-bin hist -> base[]
    unsigned v0 = h[t * 4], v1 = h[t * 4 + 1], v2 = h[t * 4 + 2], v3 = h[t * 4 + 3];
    unsigned s1 = v0, s2 = v0 + v1, s3 = v0 + v1 + v2;
    part[t] = s3 + v3;
    __syncthreads();
    for (int off = 1; off < 256; off <<= 1) {
        unsigned x = (t >= off) ? part[t - off] : 0u;
        __syncthreads();
        part[t] += x;
        __syncthreads();
    }
    unsigned tb = (t > 0) ? part[t - 1] : 0u;
    unsigned segstart = (unsigned)seg * (unsigned)SEG;
    base[t * 4] = segstart + tb;
    base[t * 4 + 1] = segstart + tb + s1;
    base[t * 4 + 2] = segstart + tb + s2;
    base[t * 4 + 3] = segstart + tb + s3;
    __syncthreads();
    // chunk-axis scans: 4 waves x 4 bins, wave-shuffle scan (no barriers)
    int wave = t >> 6, lane = t & 63;
    int c0 = seg * (SEG / CHUNK);
    for (int j = wave; j < 16; j += 4) {
        int b = grp * 16 + j;
        unsigned run = 0;
        for (int r = 0; r < 4; ++r) {  // 4 x 64 = 256 chunks per segment
            int c = r * 64 + lane;
            unsigned v = (c0 + c < nchunks) ? chist[(size_t)(c0 + c) * K + b] : 0u;
            unsigned x = v;
            for (int d = 1; d < 64; d <<= 1) {
                unsigned y = __shfl_up(x, d);
                if (lane >= d) x += y;
            }
            cursor[((size_t)seg * K + b) * 256 + c] = base[b] + (x - v) + run;
            run += __shfl(x, 63);
        }
    }
}

// ---- kernel B (slim): partition using precomputed chist + cursor ----
__global__ __launch_bounds__(256) void partition_kernel(
    const float2* __restrict__ uv, const unsigned* __restrict__ chist,
    const unsigned* __restrict__ cursor, float2* __restrict__ uv_s,
    unsigned* __restrict__ invp, int n, int pinned) {
    __shared__ float2 ssort[CHUNK];   // 32 KB
    __shared__ unsigned cnt[K];       // 4 KB
    __shared__ unsigned lbase[K];     // 4 KB
    __shared__ unsigned gdiff[K];     // 4 KB
    __shared__ unsigned part[256];    // 1 KB
    int t = threadIdx.x;
    int blk = blockIdx.x;
    int c = pinned ? ((blk % NXCD) * (SEG / CHUNK) + blk / NXCD) : blk;
    int cb = c * CHUNK;
    if (cb >= n) return;
    int cnum = min(CHUNK, n - cb);
    int seg = c / (SEG / CHUNK);
    int cidx = c % (SEG / CHUNK);

    // load this chunk's hist (coalesced 16B) + local exclusive scan -> lbase;
    // gdiff[b] = deterministic global base - lbase (no atomics anywhere)
    u32x4 hv = *(const u32x4*)(chist + (size_t)c * K + t * 4);
    {
        unsigned s1 = hv.x, s2 = hv.x + hv.y, s3 = hv.x + hv.y + hv.z;
        part[t] = s3 + hv.w;
        __syncthreads();
        for (int off = 1; off < 256; off <<= 1) {
            unsigned x = (t >= off) ? part[t - off] : 0u;
            __syncthreads();
            part[t] += x;
            __syncthreads();
        }
        unsigned tb = (t > 0) ? part[t - 1] : 0u;
        unsigned lb[4] = {tb, tb + s1, tb + s2, tb + s3};
        for (int j = 0; j < 4; ++j) {
            int b = t * 4 + j;
            lbase[b] = lb[j];
            gdiff[b] = cursor[((size_t)seg * K + b) * (SEG / CHUNK) + cidx] - lb[j];
            cnt[b] = 0u;
        }
    }
    __syncthreads();
    // rank pass: single uv read; stage into bin-sorted LDS slots; write inv
    const f32x4* uv4 = (const f32x4*)(uv + cb);
    int npair = cnum >> 1;
    for (int k2 = t; k2 < npair; k2 += 256) {
        f32x4 q = uv4[k2];
        int ba = binof(q.x, q.y);
        unsigned sa = lbase[ba] + atomicAdd(&cnt[ba], 1u);
        ssort[sa] = make_float2(q.x, q.y);
        int bb = binof(q.z, q.w);
        unsigned sb = lbase[bb] + atomicAdd(&cnt[bb], 1u);
        ssort[sb] = make_float2(q.z, q.w);
        if (invp) {
            u32x2 iv;
            iv.x = gdiff[ba] + sa;
            iv.y = gdiff[bb] + sb;
            *(u32x2*)(invp + cb + k2 * 2) = iv;
        }
    }
    if ((cnum & 1) && t == 0) {
        float2 q = uv[cb + cnum - 1];
        int b = binof(q.x, q.y);
        unsigned s = lbase[b] + atomicAdd(&cnt[b], 1u);
        ssort[s] = q;
        if (invp) invp[cb + cnum - 1] = gdiff[b] + s;
    }
    __syncthreads();
    // emit coalesced (per-bin runs)
    for (int s = t; s < cnum; s += 256) {
        float2 q = ssort[s];
        int b = binof(q.x, q.y);
        uv_s[gdiff[b] + (unsigned)s] = q;
    }
}

// ---- kernel B-old (fallback middle path): partition with idx_s output ----
__global__ __launch_bounds__(256) void partition_idx_kernel(
    const float2* __restrict__ uv, const unsigned* __restrict__ hist,
    unsigned* __restrict__ cursor, float2* __restrict__ uv_s,
    unsigned* __restrict__ idxp, int n, int pinned) {
    __shared__ float2 suv[CHUNK];
    __shared__ unsigned short slid[CHUNK];
    __shared__ unsigned cnt[K];
    __shared__ unsigned lbase[K];
    __shared__ unsigned goff[K];
    __shared__ unsigned part[256];
    int t = threadIdx.x;
    int blk = blockIdx.x;
    int c = pinned ? ((blk % NXCD) * (SEG / CHUNK) + blk / NXCD) : blk;
    int cb = c * CHUNK;
    if (cb >= n) return;
    int cnum = min(CHUNK, n - cb);
    int seg = cb / SEG;
    unsigned segstart = (unsigned)((size_t)seg * SEG);
    {
        const f32x4* uv4 = (const f32x4*)(uv + cb);
        int npair = cnum >> 1;
        for (int k2 = t; k2 < npair; k2 += 256) {
            f32x4 q = uv4[k2];
            suv[k2 * 2] = make_float2(q.x, q.y);
            suv[k2 * 2 + 1] = make_float2(q.z, q.w);
        }
        if ((cnum & 1) && t == 0) suv[cnum - 1] = uv[cb + cnum - 1];
    }
    for (int b = t; b < K; b += 256) cnt[b] = 0u;
    __syncthreads();
    for (int k = t; k < cnum; k += 256)
        atomicAdd(&cnt[binof(suv[k].x, suv[k].y)], 1u);
    __syncthreads();
    {
        unsigned v0 = cnt[t * 4], v1 = cnt[t * 4 + 1], v2 = cnt[t * 4 + 2],
                 v3 = cnt[t * 4 + 3];
        unsigned s1 = v0, s2 = v0 + v1, s3 = v0 + v1 + v2;
        part[t] = s3 + v3;
        __syncthreads();
        for (int off = 1; off < 256; off <<= 1) {
            unsigned x = (t >= off) ? part[t - off] : 0u;
            __syncthreads();
            part[t] += x;
            __syncthreads();
        }
        unsigned tb = (t > 0) ? part[t - 1] : 0u;
        lbase[t * 4] = tb;
        lbase[t * 4 + 1] = tb + s1;
        lbase[t * 4 + 2] = tb + s2;
        lbase[t * 4 + 3] = tb + s3;
    }
    __syncthreads();
    {
        const unsigned* h = hist + (size_t)seg * K;
        unsigned v0 = h[t * 4], v1 = h[t * 4 + 1], v2 = h[t * 4 + 2],
                 v3 = h[t * 4 + 3];
        unsigned s1 = v0, s2 = v0 + v1, s3 = v0 + v1 + v2;
        part[t] = s3 + v3;
        __syncthreads();
        for (int off = 1; off < 256; off <<= 1) {
            unsigned x = (t >= off) ? part[t - off] : 0u;
            __syncthreads();
            part[t] += x;
            __syncthreads();
        }
        unsigned tb = (t > 0) ? part[t - 1] : 0u;
        unsigned sbv[4] = {tb, tb + s1, tb + s2, tb + s3};
        for (int j = 0; j < 4; ++j) {
            int b = t * 4 + j;
            unsigned cc = cnt[b];
            unsigned r = cc ? atomicAdd(&cursor[(size_t)seg * K + b], cc) : 0u;
            goff[b] = segstart + sbv[j] + r;
        }
    }
    __syncthreads();
    for (int b = t; b < K; b += 256) cnt[b] = 0u;
    __syncthreads();
    for (int k = t; k < cnum; k += 256) {
        int b = binof(suv[k].x, suv[k].y);
        unsigned r = atomicAdd(&cnt[b], 1u);
        slid[lbase[b] + r] = (unsigned short)k;
    }
    __syncthreads();
    for (int s = t; s < cnum; s += 256) {
        int lid = slid[s];
        float2 q = suv[lid];
        int b = binof(q.x, q.y);
        unsigned pos = goff[b] + ((unsigned)s - lbase[b]);
        uv_s[pos] = q;
        idxp[pos] = (unsigned)(cb + lid);
    }
}

// ---- bilinear tap from row-pair half2 texture ----
__device__ __forceinline__ float sample_level(const __half2* __restrict__ R,
                                              const int S, const float gx,
                                              const float gy) {
    const float halfS = 0.5f * (float)S;
    float x = (gx + 1.0f) * halfS - 0.5f;
    float y = (gy + 1.0f) * halfS - 0.5f;
    float xf = floorf(x), yf = floorf(y);
    float wx = x - xf, wy = y - yf;
    int x0 = (int)xf, y0 = (int)yf;

    int yc = min(max(y0, 0), S - 1);
    float wa = (y0 >= 0) ? (1.0f - wy) : wy;
    if (y0 < -1 || y0 >= S) wa = 0.0f;
    float wb = (y0 >= 0 && y0 < S - 1) ? wy : 0.0f;

    int xb = min(max(x0, 0), S - 2);
    bool xin = (x0 >= 0) && (x0 <= S - 2);
    float wxa = xin ? (1.0f - wx) : ((x0 == -1) ? wx : 0.0f);
    float wxb = xin ? wx : ((x0 == S - 1) ? (1.0f - wx) : 0.0f);

    uint2 q;
    __builtin_memcpy(&q, (const char*)(R + (size_t)yc * (size_t)S + xb), 8);
    __half2 ca = *(const __half2*)&q.x;
    __half2 cb = *(const __half2*)&q.y;
    float2 fa = __half22float2(ca);
    float2 fb = __half22float2(cb);
    float cola = fmaf(wa, fa.x, wb * fa.y);
    float colb = fmaf(wa, fb.x, wb * fb.y);
    return fmaf(wxa, cola, wxb * colb);
}

__device__ __forceinline__ float sample_point(const __half2* __restrict__ r1,
                                              const __half2* __restrict__ r2,
                                              const __half2* __restrict__ r3,
                                              const __half2* __restrict__ r4,
                                              float ux, float uy) {
    float gx = ux * 2.0f - 1.0f;
    float gy = uy * 2.0f - 1.0f;
    float acc = sample_level(r1, 2048, gx, gy);
    acc += sample_level(r2, 1024, gx, gy);
    acc += sample_level(r3, 512, gx, gy);
    acc += sample_level(r4, 256, gx, gy);
    return acc;
}

// ---- kernel C: sample in sorted order -> val_s (fully coalesced) ----
__global__ __launch_bounds__(256) void lappyr_sample4(
    const float2* __restrict__ uv_s, const __half2* __restrict__ r1,
    const __half2* __restrict__ r2, const __half2* __restrict__ r3,
    const __half2* __restrict__ r4, float* __restrict__ val_s, int n,
    int pinned) {
    int blk = blockIdx.x;
    int sb = pinned ? ((blk % NXCD) * (SEG / 1024) + blk / NXCD) : blk;
    int base = sb * 1024 + threadIdx.x * 4;
    if (base + 3 < n) {
        const f32x4* u4 = (const f32x4*)(uv_s + base);
        f32x4 a = __builtin_nontemporal_load(u4);
        f32x4 b = __builtin_nontemporal_load(u4 + 1);
        f32x4 res;
        res.x = sample_point(r1, r2, r3, r4, a.x, a.y);
        res.y = sample_point(r1, r2, r3, r4, a.z, a.w);
        res.z = sample_point(r1, r2, r3, r4, b.x, b.y);
        res.w = sample_point(r1, r2, r3, r4, b.z, b.w);
        *(f32x4*)(val_s + base) = res;
    } else {
        for (int j = 0; j < 4; ++j) {
            int p = base + j;
            if (p < n) {
                float2 q = uv_s[p];
                val_s[p] = sample_point(r1, r2, r3, r4, q.x, q.y);
            }
        }
    }
}

// ---- kernel D: out[p] = val_s[inv[p]] (random READS, pinned L2 window) ----
__global__ __launch_bounds__(256) void lappyr_unsort4(
    const unsigned* __restrict__ inv, const float* __restrict__ val_s,
    float* __restrict__ out, int n, int pinned) {
    int blk = blockIdx.x;
    int sb = pinned ? ((blk % NXCD) * (SEG / 1024) + blk / NXCD) : blk;
    int base = sb * 1024 + threadIdx.x * 4;
    if (base + 3 < n) {
        u32x4 iv = __builtin_nontemporal_load((const u32x4*)(inv + base));
        f32x4 res;
        res.x = val_s[iv.x];
        res.y = val_s[iv.y];
        res.z = val_s[iv.z];
        res.w = val_s[iv.w];
        __builtin_nontemporal_store(res, (f32x4*)(out + base));
    } else {
        for (int j = 0; j < 4; ++j) {
            int p = base + j;
            if (p < n) out[p] = val_s[inv[p]];
        }
    }
}

// ---- middle fallback: fused sample+scatter (2 pts/thread) ----
__global__ __launch_bounds__(256) void lappyr_sample_sorted(
    const float2* __restrict__ uv_s, const unsigned* __restrict__ idx_s,
    const __half2* __restrict__ r1, const __half2* __restrict__ r2,
    const __half2* __restrict__ r3, const __half2* __restrict__ r4,
    float* __restrict__ out, int n, int pinned) {
    int blk = blockIdx.x;
    int sb = pinned ? ((blk % NXCD) * (SEG / 512) + blk / NXCD) : blk;
    int i = sb * 256 + threadIdx.x;
    int p0 = i * 2;
    if (p0 >= n) return;
    if (p0 + 1 < n) {
        f32x4 q = __builtin_nontemporal_load((const f32x4*)uv_s + i);
        u32x2 id = __builtin_nontemporal_load((const u32x2*)idx_s + i);
        float a0 = sample_point(r1, r2, r3, r4, q.x, q.y);
        float a1 = sample_point(r1, r2, r3, r4, q.z, q.w);
        out[id.x] = a0;
        out[id.y] = a1;
    } else {
        float2 q = uv_s[p0];
        out[idx_s[p0]] = sample_point(r1, r2, r3, r4, q.x, q.y);
    }
}

// ---- fallback A: unsorted sampling over repacked levels ----
__global__ __launch_bounds__(256) void lappyr_sample_kernel(
    const float2* __restrict__ uv, const __half2* __restrict__ r1,
    const __half2* __restrict__ r2, const __half2* __restrict__ r3,
    const __half2* __restrict__ r4, float* __restrict__ out, int n) {
    int i = blockIdx.x * blockDim.x + threadIdx.x;
    if (i >= n) return;
    float2 p = uv[i];
    out[i] = sample_point(r1, r2, r3, r4, p.x, p.y);
}

// ---- fallback B (ws too small): direct f32 sampling ----
__device__ __forceinline__ float bilin_f32(const float* __restrict__ img,
                                           const int S, const float gx,
                                           const float gy) {
    const float halfS = 0.5f * (float)S;
    float x = (gx + 1.0f) * halfS - 0.5f;
    float y = (gy + 1.0f) * halfS - 0.5f;
    float xf = floorf(x), yf = floorf(y);
    float wx = x - xf, wy = y - yf;
    int x0 = (int)xf, y0 = (int)yf, x1 = x0 + 1, y1 = y0 + 1;
    float ex0 = (x0 >= 0 && x0 < S) ? (1.0f - wx) : 0.0f;
    float ex1 = (x1 >= 0 && x1 < S) ? wx : 0.0f;
    float ey0 = (y0 >= 0 && y0 < S) ? (1.0f - wy) : 0.0f;
    float ey1 = (y1 >= 0 && y1 < S) ? wy : 0.0f;
    int xc0 = min(max(x0, 0), S - 1), xc1 = min(max(x1, 0), S - 1);
    int yc0 = min(max(y0, 0), S - 1), yc1 = min(max(y1, 0), S - 1);
    const float* r0 = img + (size_t)yc0 * S;
    const float* r1 = img + (size_t)yc1 * S;
    return ey0 * fmaf(ex0, r0[xc0], ex1 * r0[xc1]) +
           ey1 * fmaf(ex0, r1[xc0], ex1 * r1[xc1]);
}

__global__ __launch_bounds__(256) void lappyr_f32_kernel(
    const float2* __restrict__ uv, const float* __restrict__ l1,
    const float* __restrict__ l2, const float* __restrict__ l3,
    const float* __restrict__ l4, float* __restrict__ out, int n) {
    int i = blockIdx.x * blockDim.x + threadIdx.x;
    if (i >= n) return;
    float2 p = uv[i];
    float gx = p.x * 2.0f - 1.0f;
    float gy = p.y * 2.0f - 1.0f;
    float acc = bilin_f32(l1, 2048, gx, gy);
    acc += bilin_f32(l2, 1024, gx, gy);
    acc += bilin_f32(l3, 512, gx, gy);
    acc += bilin_f32(l4, 256, gx, gy);
    out[i] = acc;
}

extern "C" void kernel_launch(void* const* d_in, const int* in_sizes, int n_in,
                              void* d_out, int out_size, void* d_ws, size_t ws_size,
                              hipStream_t stream) {
    const float2* uv = (const float2*)d_in[0];
    const float* l1 = (const float*)d_in[1];
    const float* l2 = (const float*)d_in[2];
    const float* l3 = (const float*)d_in[3];
    const float* l4 = (const float*)d_in[4];
    float* out = (float*)d_out;
    int n = out_size;

    const size_t n1 = 2048u * 2048u, n2 = 1024u * 1024u, n3 = 512u * 512u,
                 n4 = 256u * 256u;
    const size_t ntot = n1 + n2 + n3 + n4;
    const size_t rep_bytes = ntot * sizeof(__half2);  // ~21.25 MiB

    int nseg = (n + SEG - 1) / SEG;
    int nchunks = (n + CHUNK - 1) / CHUNK;
    int cps = SEG / CHUNK;  // 256 chunks per segment

    // deterministic tables (aliased into val slab; dead until sample4):
    //   chist[nseg*256][K] | seghist[nseg][K] | cursor[nseg][K][256]
    size_t chist_b = (size_t)nseg * cps * K * 4;   // 1 MB per segment
    size_t seg_b = (size_t)nseg * K * 4;           // 4 KB per segment
    size_t tbl = chist_b + seg_b + chist_b;
    size_t val_region = ((size_t)n * 4 > tbl) ? (size_t)n * 4 : tbl;

    // gather-unsort layout: rep | uv_s | inv | val_region
    size_t off_uvs = (rep_bytes + 255) & ~(size_t)255;
    size_t off_inv = off_uvs + (size_t)n * 8;
    size_t off_val = (off_inv + (size_t)n * 4 + 255) & ~(size_t)255;
    size_t need2 = off_val + val_region;
    // scatter layout (middle fallback): rep | uv_s | idx | hist | cursor
    size_t tbl1 = (size_t)nseg * K * 4 * 2;
    size_t off_idx = off_uvs + (size_t)n * 8;
    size_t off_hist1 = (off_idx + (size_t)n * 4 + 255) & ~(size_t)255;
    size_t need1 = off_hist1 + tbl1;

    int repack_blocks = (int)((ntot / 4 + 255) / 256);

    if (ws_size >= rep_bytes) {
        char* ws = (char*)d_ws;
        __half2* r1 = (__half2*)ws;
        __half2* r2 = r1 + n1;
        __half2* r3 = r2 + n2;
        __half2* r4 = r3 + n3;
        int pinned = (n == NXCD * SEG) ? 1 : 0;
        int hist_blocks = (n + HB - 1) / HB;
        int ga = max(repack_blocks, hist_blocks);
        if (ws_size >= need2 && n > 0) {
            float2* uv_s = (float2*)(ws + off_uvs);
            unsigned* inv = (unsigned*)(ws + off_inv);
            float* val_s = (float*)(ws + off_val);
            unsigned* chist = (unsigned*)(ws + off_val);
            unsigned* seghist = (unsigned*)(ws + off_val + chist_b);
            unsigned* cursor = (unsigned*)(ws + off_val + chist_b + seg_b);
            // zero chist (stale trailing chunks) + seghist in one contiguous shot
            (void)hipMemsetAsync(chist, 0, chist_b + seg_b, stream);
            repack_hist_kernel<<<ga, 256, 0, stream>>>(l1, l2, l3, l4, r1, r2, r3,
                                                       r4, uv, seghist, chist, n);
            cursor_kernel<<<nseg * 64, 256, 0, stream>>>(seghist, chist, cursor,
                                                         nchunks);
            partition_kernel<<<nchunks, 256, 0, stream>>>(uv, chist, cursor, uv_s,
                                                          inv, n, pinned);
            int nb4 = (n + 1023) / 1024;
            lappyr_sample4<<<nb4, 256, 0, stream>>>(uv_s, r1, r2, r3, r4, val_s,
                                                    n, pinned);
            lappyr_unsort4<<<nb4, 256, 0, stream>>>(inv, val_s, out, n, pinned);
        } else if (ws_size >= need1 && n > 0) {
            float2* uv_s = (float2*)(ws + off_uvs);
            unsigned* idx_s = (unsigned*)(ws + off_idx);
            unsigned* hist = (unsigned*)(ws + off_hist1);
            unsigned* cursor = hist + (size_t)nseg * K;
            (void)hipMemsetAsync(hist, 0, tbl1, stream);
            repack_hist_kernel<<<ga, 256, 0, stream>>>(l1, l2, l3, l4, r1, r2, r3,
                                                       r4, uv, hist, nullptr, n);
            partition_idx_kernel<<<nchunks, 256, 0, stream>>>(
                uv, hist, cursor, uv_s, idx_s, n, pinned);
            int nh = (n + 1) / 2;
            lappyr_sample_sorted<<<(nh + 255) / 256, 256, 0, stream>>>(
                uv_s, idx_s, r1, r2, r3, r4, out, n, pinned);
        } else {
            repack_hist_kernel<<<repack_blocks, 256, 0, stream>>>(
                l1, l2, l3, l4, r1, r2, r3, r4, uv, nullptr, nullptr, n);
            lappyr_sample_kernel<<<(n + 255) / 256, 256, 0, stream>>>(
                uv, r1, r2, r3, r4, out, n);
        }
    } else {
        lappyr_f32_kernel<<<(n + 255) / 256, 256, 0, stream>>>(uv, l1, l2, l3, l4,
                                                               out, n);
    }
}